// Round 5
// baseline (721.295 us; speedup 1.0000x reference)
//
#include <hip/hip_runtime.h>

typedef unsigned short u16;
typedef __attribute__((ext_vector_type(8))) unsigned short u16x8;
typedef __attribute__((ext_vector_type(8))) __bf16 bf16x8;
typedef __attribute__((ext_vector_type(4))) float f32x4;

#define DEV __device__ __forceinline__

DEV u16 f2bf(float f) {
  unsigned u = __builtin_bit_cast(unsigned, f);
  u += 0x7FFFu + ((u >> 16) & 1u);
  return (u16)(u >> 16);
}
DEV float bf2f(u16 h) {
  unsigned u = ((unsigned)h) << 16;
  return __builtin_bit_cast(float, u);
}
DEV f32x4 mfma16(u16x8 a, u16x8 b, f32x4 c) {
  return __builtin_amdgcn_mfma_f32_16x16x32_bf16(
      __builtin_bit_cast(bf16x8, a), __builtin_bit_cast(bf16x8, b), c, 0, 0, 0);
}
DEV void gload_lds16(const void* g, void* l) {
  __builtin_amdgcn_global_load_lds(
      (const __attribute__((address_space(1))) void*)g,
      (__attribute__((address_space(3))) void*)l, 16, 0, 0);
}

// ---------------- weight cast fp32 -> bf16 ----------------
__global__ __launch_bounds__(256) void cast_w(const float* __restrict__ in, u16* __restrict__ out) {
  size_t i = ((size_t)blockIdx.x * 256 + threadIdx.x) * 8;
  float4 a = *(const float4*)(in + i);
  float4 b = *(const float4*)(in + i + 4);
  u16x8 o;
  o[0] = f2bf(a.x); o[1] = f2bf(a.y); o[2] = f2bf(a.z); o[3] = f2bf(a.w);
  o[4] = f2bf(b.x); o[5] = f2bf(b.y); o[6] = f2bf(b.z); o[7] = f2bf(b.w);
  *(u16x8*)(out + i) = o;
}

// ---------------- RMSNorm (fp32 in) -> bf16 out ----------------
__global__ __launch_bounds__(256) void rmsnorm_cast(const float* __restrict__ x, const float* __restrict__ w,
                                                    u16* __restrict__ out) {
  const int row = blockIdx.x, tid = threadIdx.x;
  const float* xr = x + (size_t)row * 2048;
  float4 a = *(const float4*)(xr + tid * 8);
  float4 b = *(const float4*)(xr + tid * 8 + 4);
  float ss = a.x * a.x + a.y * a.y + a.z * a.z + a.w * a.w +
             b.x * b.x + b.y * b.y + b.z * b.z + b.w * b.w;
#pragma unroll
  for (int off = 32; off; off >>= 1) ss += __shfl_xor(ss, off);
  __shared__ float part[4];
  if ((tid & 63) == 0) part[tid >> 6] = ss;
  __syncthreads();
  float tot = part[0] + part[1] + part[2] + part[3];
  float r = rsqrtf(tot * (1.0f / 2048.0f) + 1e-5f);
  float4 wa = *(const float4*)(w + tid * 8);
  float4 wb = *(const float4*)(w + tid * 8 + 4);
  u16x8 o;
  o[0] = f2bf(a.x * r * wa.x); o[1] = f2bf(a.y * r * wa.y);
  o[2] = f2bf(a.z * r * wa.z); o[3] = f2bf(a.w * r * wa.w);
  o[4] = f2bf(b.x * r * wb.x); o[5] = f2bf(b.y * r * wb.y);
  o[6] = f2bf(b.z * r * wb.z); o[7] = f2bf(b.w * r * wb.w);
  *(u16x8*)(out + (size_t)row * 2048 + tid * 8) = o;
}

// ============ 256x256-tile, 8-wave, 8-phase NT GEMM (counted vmcnt) ============
template <int EPI>
__global__ __launch_bounds__(512) void gemm8(const u16* __restrict__ Ag, const u16* __restrict__ Bg,
                                             void* __restrict__ outp, const void* __restrict__ extra,
                                             int M, int N, int KC, int lda, int ldb, int koffStride,
                                             long long bStrideB, long long bStrideO) {
  __shared__ u16 lds[32768];  // 64 KiB
  const int z = blockIdx.z;
  const u16* Ap = Ag;
  const u16* Bp = Bg + (EPI == 0 ? (size_t)z * bStrideB : (size_t)0);
  const int koff = (EPI == 3) ? z * koffStride : 0;
  const int nbx = N >> 8;
  const int q8 = gridDim.x >> 3;  // grids are multiples of 8
  const int gid = blockIdx.x;
  const int lid = (gid & 7) * q8 + (gid >> 3);  // XCD-contiguous logical id (T1)
  const int by = lid / nbx, bx = lid % nbx;
  const int bm = by << 8, bn = bx << 8;
  const int tid = threadIdx.x;
  const int w = tid >> 6, l = tid & 63;
  const int wr = w >> 2, wc = w & 3;
  const int l16 = l & 15, l4 = l >> 4;
  const int NT2 = KC >> 6, NTT = KC >> 5;
  const int srow = (w << 4) + (l >> 2);
  const int scolb = ((l & 3) << 4) ^ (((l >> 3) & 1) << 5) ^ (((l >> 4) & 1) << 4);
  char* ldsb = (char*)lds;

  auto STG = [&](const u16* src, int ldx, int rowBase, int kt, int ldsOffU16) {
    const char* g = (const char*)src + ((size_t)(rowBase + srow) * ldx + kt) * 2 + scolb;
    gload_lds16(g, ldsb + ldsOffU16 * 2 + (w << 10));
  };

  f32x4 acc[8][4] = {};
  u16x8 a[4], b[4];

  auto LDA4 = [&](int bufU16, int mh) {
#pragma unroll
    for (int j = 0; j < 4; ++j) {
      int row = wr * 128 + mh * 64 + j * 16 + l16;
      int off = (row << 5) + (l4 << 3);
      off ^= (((row >> 1) & 1) << 4) | (((row >> 2) & 1) << 3);
      a[j] = *(const u16x8*)(lds + bufU16 + off);
    }
  };
  auto LDB2 = [&](int bufU16, int nh) {
#pragma unroll
    for (int j = 0; j < 2; ++j) {
      int row = wc * 64 + nh * 32 + j * 16 + l16;
      int off = (row << 5) + (l4 << 3);
      off ^= (((row >> 1) & 1) << 4) | (((row >> 2) & 1) << 3);
      b[nh * 2 + j] = *(const u16x8*)(lds + bufU16 + 8192 + off);
    }
  };
  auto MM = [&](int mh, int nh) {
    __builtin_amdgcn_s_setprio(1);
#pragma unroll
    for (int mt = 0; mt < 4; ++mt)
#pragma unroll
      for (int nt = 0; nt < 2; ++nt)
        acc[mh * 4 + mt][nh * 2 + nt] = mfma16(a[mt], b[nh * 2 + nt], acc[mh * 4 + mt][nh * 2 + nt]);
    __builtin_amdgcn_s_setprio(0);
  };

  STG(Ap, lda, bm, koff, 0);
  STG(Ap, lda, bm + 128, koff, 4096);
  STG(Bp, ldb, bn, koff, 8192);
  STG(Bp, ldb, bn + 128, koff, 12288);
  STG(Ap, lda, bm, koff + 32, 16384);
  STG(Ap, lda, bm + 128, koff + 32, 20480);
  asm volatile("s_waitcnt vmcnt(2)" ::: "memory");
  __builtin_amdgcn_sched_barrier(0);
  __builtin_amdgcn_s_barrier();

  for (int it = 0; it < NT2; ++it) {
    const int t1 = 2 * it + 1, t2 = 2 * it + 2, t3 = 2 * it + 3;
    const int k1 = koff + (t1 < NTT ? t1 * 32 : 0);
    const int k2 = koff + (t2 < NTT ? t2 * 32 : 0);
    const int k3 = koff + (t3 < NTT ? t3 * 32 : 0);
    LDA4(0, 0); LDB2(0, 0);
    STG(Bp, ldb, bn, k1, 24576);
    __builtin_amdgcn_s_barrier();
    MM(0, 0);
    __builtin_amdgcn_s_barrier();
    LDB2(0, 1);
    STG(Bp, ldb, bn + 128, k1, 28672);
    __builtin_amdgcn_s_barrier();
    MM(0, 1);
    __builtin_amdgcn_s_barrier();
    LDA4(0, 1);
    __builtin_amdgcn_s_barrier();
    MM(1, 0);
    __builtin_amdgcn_s_barrier();
    STG(Ap, lda, bm, k2, 0);
    STG(Ap, lda, bm + 128, k2, 4096);
    asm volatile("s_waitcnt vmcnt(2)" ::: "memory");
    __builtin_amdgcn_sched_barrier(0);
    __builtin_amdgcn_s_barrier();
    MM(1, 1);
    __builtin_amdgcn_s_barrier();
    LDA4(16384, 0); LDB2(16384, 0);
    STG(Bp, ldb, bn, k2, 8192);
    __builtin_amdgcn_s_barrier();
    MM(0, 0);
    __builtin_amdgcn_s_barrier();
    LDB2(16384, 1);
    STG(Bp, ldb, bn + 128, k2, 12288);
    __builtin_amdgcn_s_barrier();
    MM(0, 1);
    __builtin_amdgcn_s_barrier();
    LDA4(16384, 1);
    __builtin_amdgcn_s_barrier();
    MM(1, 0);
    __builtin_amdgcn_s_barrier();
    STG(Ap, lda, bm, k3, 16384);
    STG(Ap, lda, bm + 128, k3, 20480);
    asm volatile("s_waitcnt vmcnt(2)" ::: "memory");
    __builtin_amdgcn_sched_barrier(0);
    __builtin_amdgcn_s_barrier();
    MM(1, 1);
    __builtin_amdgcn_s_barrier();
  }

#pragma unroll
  for (int i = 0; i < 8; ++i)
#pragma unroll
    for (int j = 0; j < 4; ++j)
#pragma unroll
      for (int r = 0; r < 4; ++r) {
        const int row = bm + wr * 128 + i * 16 + l4 * 4 + r;
        const int col = bn + wc * 64 + j * 16 + l16;
        const size_t idx = (size_t)row * N + col;
        float v = acc[i][j][r];
        if (EPI == 0) {
          ((u16*)outp)[(size_t)z * bStrideO + idx] = f2bf(v);
        } else if (EPI == 1) {
          ((float*)outp)[idx] = v + ((const float*)extra)[idx];
        } else if (EPI == 2) {
          float g = bf2f(((const u16*)extra)[idx]);
          float sig = 1.0f / (1.0f + __expf(-v));
          ((u16*)outp)[idx] = f2bf(g * v * sig);
        } else {
          ((float*)outp)[(size_t)z * M * N + idx] = v;
        }
      }
}

// ---------------- split-K reduce: out = p0+p1+p2+p3 + res ----------------
__global__ __launch_bounds__(256) void reduce4(const float* __restrict__ p, const float* __restrict__ res,
                                               float* __restrict__ out, size_t n) {
  size_t i = ((size_t)blockIdx.x * 256 + threadIdx.x) * 4;
  float4 a = *(const float4*)(p + i);
  float4 b = *(const float4*)(p + n + i);
  float4 c = *(const float4*)(p + 2 * n + i);
  float4 d = *(const float4*)(p + 3 * n + i);
  float4 r = *(const float4*)(res + i);
  float4 o;
  o.x = a.x + b.x + c.x + d.x + r.x;
  o.y = a.y + b.y + c.y + d.y + r.y;
  o.z = a.z + b.z + c.z + d.z + r.z;
  o.w = a.w + b.w + c.w + d.w + r.w;
  *(float4*)(out + i) = o;
}

// ---------------- RoPE ----------------
__global__ __launch_bounds__(256) void rope_table(float2* __restrict__ tab) {
  int idx = blockIdx.x * 256 + threadIdx.x;  // S*32 = 65536
  int pos = idx >> 5, i = idx & 31;
  float inv = __expf(-(float)(2 * i) * (9.210340371976184f / 64.0f));
  float a = (float)pos * inv;
  float s, c;
  __sincosf(a, &s, &c);
  tab[idx] = make_float2(c, s);
}

__global__ __launch_bounds__(256) void rope_apply(u16* __restrict__ q, u16* __restrict__ k,
                                                  const float2* __restrict__ tab) {
  int idx = blockIdx.x * 256 + threadIdx.x;  // S*H*32 = 2M
  int i = idx & 31;
  int hh = (idx >> 5) & 31;
  int pos = idx >> 10;
  float2 cs = tab[(pos << 5) + i];
  size_t base = (size_t)pos * 2048 + hh * 64 + i;
  float a0 = bf2f(q[base]), a1 = bf2f(q[base + 32]);
  q[base] = f2bf(a0 * cs.x - a1 * cs.y);
  q[base + 32] = f2bf(a1 * cs.x + a0 * cs.y);
  float b0 = bf2f(k[base]), b1 = bf2f(k[base + 32]);
  k[base] = f2bf(b0 * cs.x - b1 * cs.y);
  k[base + 32] = f2bf(b1 * cs.x + b0 * cs.y);
}

// ---------------- V transpose: v[S][D] -> vT[h][d][S] ----------------
__global__ __launch_bounds__(256) void transpose_v(const u16* __restrict__ v, u16* __restrict__ vt) {
  __shared__ u16 t[64][72];
  const int t0 = blockIdx.x * 64, h = blockIdx.y, tid = threadIdx.x;
  {
    const int r = tid >> 3, c8 = (tid & 7) * 8;
#pragma unroll
    for (int j = 0; j < 2; ++j) {
      u16x8 val = *(const u16x8*)(v + (size_t)(t0 + r + 32 * j) * 2048 + h * 64 + c8);
      *(u16x8*)&t[r + 32 * j][c8] = val;
    }
  }
  __syncthreads();
  const int d = tid >> 2, q = (tid & 3) * 16;
  u16x8 lo, hi;
#pragma unroll
  for (int e = 0; e < 8; ++e) lo[e] = t[q + e][d];
#pragma unroll
  for (int e = 0; e < 8; ++e) hi[e] = t[q + 8 + e][d];
  *(u16x8*)(vt + (size_t)(h * 64 + d) * 2048 + t0 + q) = lo;
  *(u16x8*)(vt + (size_t)(h * 64 + d) * 2048 + t0 + q + 8) = hi;
}

// ---------------- Flash attention v3 ----------------
// grid (S/128, H), 256 threads = 4 waves, 32 q-rows/wave (round-3 shape).
// + double-buffered K register prefetch (kfA/kfB, static ping-pong)
// + stage-parallel softmax shuffle reductions (8 independent rows interleaved)
__global__ __launch_bounds__(256) void flash_attn(const u16* __restrict__ qb, const u16* __restrict__ kb,
                                                  const u16* __restrict__ vt, u16* __restrict__ ob) {
  const int h = blockIdx.y;
  const int q0 = blockIdx.x * 128;
  const int w = threadIdx.x >> 6, l = threadIdx.x & 63;
  const int l16 = l & 15, l4 = l >> 4;
  const float C = 0.125f * 1.4426950408889634f;  // exp2-domain scale
  __shared__ u16 P[4][32][72];
  u16x8 qf[2][2];
#pragma unroll
  for (int rt = 0; rt < 2; ++rt)
#pragma unroll
    for (int kh = 0; kh < 2; ++kh)
      qf[rt][kh] = *(const u16x8*)(qb + (size_t)(q0 + w * 32 + rt * 16 + l16) * 2048 + h * 64 + kh * 32 + l4 * 8);
  float mrun[8], lrun[8];
  f32x4 oacc[2][4] = {};
#pragma unroll
  for (int i = 0; i < 8; ++i) { mrun[i] = -1e30f; lrun[i] = 0.f; }

  u16x8 kfA[4][2], kfB[4][2];

  auto LOADK = [&](int t0, u16x8 (&kf)[4][2]) {
#pragma unroll
    for (int tt = 0; tt < 4; ++tt)
#pragma unroll
      for (int kh = 0; kh < 2; ++kh)
        kf[tt][kh] = *(const u16x8*)(kb + (size_t)(t0 + tt * 16 + l16) * 2048 + h * 64 + kh * 32 + l4 * 8);
  };

  auto TILE = [&](int t0, u16x8 (&kf)[4][2]) {
    f32x4 sacc[2][4] = {};
#pragma unroll
    for (int kh = 0; kh < 2; ++kh)
#pragma unroll
      for (int rt = 0; rt < 2; ++rt)
#pragma unroll
        for (int tt = 0; tt < 4; ++tt)
          sacc[rt][tt] = mfma16(qf[rt][kh], kf[tt][kh], sacc[rt][tt]);
    // scaled scores: row i = rt*4+r (q-row pr = (i>>2)*16 + l4*4 + (i&3)), col tt
    float v[8][4];
    float mx[8];
#pragma unroll
    for (int i = 0; i < 8; ++i) {
      const int rt = i >> 2, r = i & 3;
#pragma unroll
      for (int tt = 0; tt < 4; ++tt) v[i][tt] = sacc[rt][tt][r] * C;
      mx[i] = fmaxf(fmaxf(v[i][0], v[i][1]), fmaxf(v[i][2], v[i][3]));
    }
    // stage-parallel max reduce across 16 lanes (4 stages, 8 independent rows each)
#pragma unroll
    for (int s = 1; s <= 8; s <<= 1)
#pragma unroll
      for (int i = 0; i < 8; ++i) mx[i] = fmaxf(mx[i], __shfl_xor(mx[i], s));
    float sfac[8], ps[8];
#pragma unroll
    for (int i = 0; i < 8; ++i) {
      float mnew = fmaxf(mrun[i], mx[i]);
      sfac[i] = exp2f(mrun[i] - mnew);
      mrun[i] = mnew;
      float p0 = exp2f(v[i][0] - mnew), p1 = exp2f(v[i][1] - mnew);
      float p2 = exp2f(v[i][2] - mnew), p3 = exp2f(v[i][3] - mnew);
      const int pr = (i >> 2) * 16 + l4 * 4 + (i & 3);
      P[w][pr][l16] = f2bf(p0);
      P[w][pr][16 + l16] = f2bf(p1);
      P[w][pr][32 + l16] = f2bf(p2);
      P[w][pr][48 + l16] = f2bf(p3);
      ps[i] = (p0 + p1) + (p2 + p3);
    }
    // stage-parallel sum reduce
#pragma unroll
    for (int s = 1; s <= 8; s <<= 1)
#pragma unroll
      for (int i = 0; i < 8; ++i) ps[i] += __shfl_xor(ps[i], s);
#pragma unroll
    for (int i = 0; i < 8; ++i) lrun[i] = lrun[i] * sfac[i] + ps[i];
    // rescale O
#pragma unroll
    for (int rt = 0; rt < 2; ++rt)
#pragma unroll
      for (int nt = 0; nt < 4; ++nt)
#pragma unroll
        for (int r = 0; r < 4; ++r)
          oacc[rt][nt][r] *= sfac[rt * 4 + r];
    // PV
#pragma unroll
    for (int ks = 0; ks < 2; ++ks) {
      u16x8 pf[2];
#pragma unroll
      for (int rt = 0; rt < 2; ++rt)
        pf[rt] = *(const u16x8*)&P[w][rt * 16 + l16][ks * 32 + l4 * 8];
#pragma unroll
      for (int nt = 0; nt < 4; ++nt) {
        u16x8 vf = *(const u16x8*)(vt + (size_t)(h * 64 + nt * 16 + l16) * 2048 + t0 + ks * 32 + l4 * 8);
#pragma unroll
        for (int rt = 0; rt < 2; ++rt)
          oacc[rt][nt] = mfma16(pf[rt], vf, oacc[rt][nt]);
      }
    }
  };

  LOADK(0, kfA);
  for (int t0 = 0; t0 < 2048; t0 += 128) {
    LOADK(t0 + 64, kfB);
    TILE(t0, kfA);
    LOADK((t0 + 128) & 2047, kfA);  // wrap-guard: last prefetch reads t=0, unused
    TILE(t0 + 64, kfB);
  }
#pragma unroll
  for (int rt = 0; rt < 2; ++rt)
#pragma unroll
    for (int r = 0; r < 4; ++r) {
      float inv = 1.0f / lrun[rt * 4 + r];
#pragma unroll
      for (int nt = 0; nt < 4; ++nt)
        ob[(size_t)(q0 + w * 32 + rt * 16 + l4 * 4 + r) * 2048 + h * 64 + nt * 16 + l16] =
            f2bf(oacc[rt][nt][r] * inv);
    }
}

extern "C" void kernel_launch(void* const* d_in, const int* in_sizes, int n_in,
                              void* d_out, int out_size, void* d_ws, size_t ws_size,
                              hipStream_t stream) {
  const float* x    = (const float*)d_in[0];
  const float* w_in = (const float*)d_in[1];
  const float* wq   = (const float*)d_in[2];
  const float* wk   = (const float*)d_in[3];
  const float* wv   = (const float*)d_in[4];
  const float* wo   = (const float*)d_in[5];
  const float* w_pn = (const float*)d_in[6];
  const float* wg   = (const float*)d_in[7];
  const float* wu   = (const float*)d_in[8];
  const float* wd   = (const float*)d_in[9];
  float* out = (float*)d_out;
  char* ws = (char*)d_ws;
  const size_t MB = 1ull << 20;
  const int S = 2048, D = 2048, FF = 8192;

  u16* W_QKV = (u16*)(ws);               // 24 MB
  u16* W_O   = (u16*)(ws + 24 * MB);     // 8 MB
  u16* W_G   = (u16*)(ws + 32 * MB);     // 32 MB
  u16* W_U   = (u16*)(ws + 64 * MB);     // 32 MB
  u16* W_D   = (u16*)(ws + 96 * MB);     // 32 MB
  u16* HB    = (u16*)(ws + 128 * MB);    // 8 MB
  u16* QKVB  = (u16*)(ws + 136 * MB);    // 24 MB (q,k,v)
  u16* VT    = (u16*)(ws + 160 * MB);    // 8 MB
  u16* ATTNB = (u16*)(ws + 168 * MB);    // 8 MB
  float* X1  = (float*)(ws + 176 * MB);  // 16 MB
  u16* H2B   = (u16*)(ws + 192 * MB);    // 8 MB
  float2* RT = (float2*)(ws + 200 * MB); // 0.5 MB
  u16* GATEB = (u16*)(ws);               // 32 MB, overlays W_QKV+W_O (dead after O-proj)
  u16* PRODB = (u16*)(ws + 136 * MB);    // 32 MB, overlays QKVB+VT (dead after attention)
  float* DP  = (float*)(ws);             // 64 MB down-proj partials
  float* OP  = (float*)(ws + 208 * MB);  // 64 MB O-proj partials (only if ws permits)
  const bool splitO = ws_size >= 272 * MB;

  rope_table<<<65536 / 256, 256, 0, stream>>>(RT);
  cast_w<<<(D * D) / 2048, 256, 0, stream>>>(wq, W_QKV);
  cast_w<<<(D * D) / 2048, 256, 0, stream>>>(wk, W_QKV + (size_t)D * D);
  cast_w<<<(D * D) / 2048, 256, 0, stream>>>(wv, W_QKV + 2 * (size_t)D * D);
  cast_w<<<(D * D) / 2048, 256, 0, stream>>>(wo, W_O);
  cast_w<<<(FF * D) / 2048, 256, 0, stream>>>(wg, W_G);
  cast_w<<<(FF * D) / 2048, 256, 0, stream>>>(wu, W_U);
  cast_w<<<(FF * D) / 2048, 256, 0, stream>>>(wd, W_D);
  rmsnorm_cast<<<S, 256, 0, stream>>>(x, w_in, HB);
  gemm8<0><<<dim3(64, 1, 3), 512, 0, stream>>>(HB, W_QKV, QKVB, nullptr, S, D, D, D, D, 0,
                                               (long long)D * D, (long long)S * D);
  rope_apply<<<(S * 32 * 32) / 256, 256, 0, stream>>>(QKVB, QKVB + (size_t)S * D, RT);
  transpose_v<<<dim3(S / 64, 32), 256, 0, stream>>>(QKVB + 2 * (size_t)S * D, VT);
  flash_attn<<<dim3(S / 128, 32), 256, 0, stream>>>(QKVB, QKVB + (size_t)S * D, VT, ATTNB);
  if (splitO) {
    gemm8<3><<<dim3(64, 1, 4), 512, 0, stream>>>(ATTNB, W_O, OP, nullptr, S, D, 512, D, D, 512, 0, 0);
    reduce4<<<(S * D) / 1024, 256, 0, stream>>>(OP, x, X1, (size_t)S * D);
  } else {
    gemm8<1><<<dim3(64, 1, 1), 512, 0, stream>>>(ATTNB, W_O, X1, x, S, D, D, D, D, 0, 0, 0);
  }
  rmsnorm_cast<<<S, 256, 0, stream>>>(X1, w_pn, H2B);
  gemm8<0><<<dim3(256, 1, 1), 512, 0, stream>>>(H2B, W_G, GATEB, nullptr, S, FF, D, D, D, 0, 0, 0);
  gemm8<2><<<dim3(256, 1, 1), 512, 0, stream>>>(H2B, W_U, PRODB, GATEB, S, FF, D, D, D, 0, 0, 0);
  gemm8<3><<<dim3(64, 1, 4), 512, 0, stream>>>(PRODB, W_D, DP, nullptr, S, D, 2048, FF, FF, 2048, 0, 0);
  reduce4<<<(S * D) / 1024, 256, 0, stream>>>(DP, X1, out, (size_t)S * D);
  (void)in_sizes; (void)n_in; (void)out_size;
}

// Round 6
// 592.971 us; speedup vs baseline: 1.2164x; 1.2164x over previous
//
#include <hip/hip_runtime.h>

typedef unsigned short u16;
typedef __attribute__((ext_vector_type(8))) unsigned short u16x8;
typedef __attribute__((ext_vector_type(8))) __bf16 bf16x8;
typedef __attribute__((ext_vector_type(4))) float f32x4;

#define DEV __device__ __forceinline__

DEV u16 f2bf(float f) {
  unsigned u = __builtin_bit_cast(unsigned, f);
  u += 0x7FFFu + ((u >> 16) & 1u);
  return (u16)(u >> 16);
}
DEV float bf2f(u16 h) {
  unsigned u = ((unsigned)h) << 16;
  return __builtin_bit_cast(float, u);
}
DEV f32x4 mfma16(u16x8 a, u16x8 b, f32x4 c) {
  return __builtin_amdgcn_mfma_f32_16x16x32_bf16(
      __builtin_bit_cast(bf16x8, a), __builtin_bit_cast(bf16x8, b), c, 0, 0, 0);
}
DEV void gload_lds16(const void* g, void* l) {
  __builtin_amdgcn_global_load_lds(
      (const __attribute__((address_space(1))) void*)g,
      (__attribute__((address_space(3))) void*)l, 16, 0, 0);
}

// ---------------- weight cast fp32 -> bf16 ----------------
__global__ __launch_bounds__(256) void cast_w(const float* __restrict__ in, u16* __restrict__ out) {
  size_t i = ((size_t)blockIdx.x * 256 + threadIdx.x) * 8;
  float4 a = *(const float4*)(in + i);
  float4 b = *(const float4*)(in + i + 4);
  u16x8 o;
  o[0] = f2bf(a.x); o[1] = f2bf(a.y); o[2] = f2bf(a.z); o[3] = f2bf(a.w);
  o[4] = f2bf(b.x); o[5] = f2bf(b.y); o[6] = f2bf(b.z); o[7] = f2bf(b.w);
  *(u16x8*)(out + i) = o;
}

// ---------------- RMSNorm (fp32 in) -> bf16 out ----------------
__global__ __launch_bounds__(256) void rmsnorm_cast(const float* __restrict__ x, const float* __restrict__ w,
                                                    u16* __restrict__ out) {
  const int row = blockIdx.x, tid = threadIdx.x;
  const float* xr = x + (size_t)row * 2048;
  float4 a = *(const float4*)(xr + tid * 8);
  float4 b = *(const float4*)(xr + tid * 8 + 4);
  float ss = a.x * a.x + a.y * a.y + a.z * a.z + a.w * a.w +
             b.x * b.x + b.y * b.y + b.z * b.z + b.w * b.w;
#pragma unroll
  for (int off = 32; off; off >>= 1) ss += __shfl_xor(ss, off);
  __shared__ float part[4];
  if ((tid & 63) == 0) part[tid >> 6] = ss;
  __syncthreads();
  float tot = part[0] + part[1] + part[2] + part[3];
  float r = rsqrtf(tot * (1.0f / 2048.0f) + 1e-5f);
  float4 wa = *(const float4*)(w + tid * 8);
  float4 wb = *(const float4*)(w + tid * 8 + 4);
  u16x8 o;
  o[0] = f2bf(a.x * r * wa.x); o[1] = f2bf(a.y * r * wa.y);
  o[2] = f2bf(a.z * r * wa.z); o[3] = f2bf(a.w * r * wa.w);
  o[4] = f2bf(b.x * r * wb.x); o[5] = f2bf(b.y * r * wb.y);
  o[6] = f2bf(b.z * r * wb.z); o[7] = f2bf(b.w * r * wb.w);
  *(u16x8*)(out + (size_t)row * 2048 + tid * 8) = o;
}

// ============ 256x256-tile, 8-wave, 8-phase NT GEMM (counted vmcnt) ============
template <int EPI>
__global__ __launch_bounds__(512) void gemm8(const u16* __restrict__ Ag, const u16* __restrict__ Bg,
                                             void* __restrict__ outp, const void* __restrict__ extra,
                                             int M, int N, int KC, int lda, int ldb, int koffStride,
                                             long long bStrideB, long long bStrideO) {
  __shared__ u16 lds[32768];  // 64 KiB
  const int z = blockIdx.z;
  const u16* Ap = Ag;
  const u16* Bp = Bg + (EPI == 0 ? (size_t)z * bStrideB : (size_t)0);
  const int koff = (EPI == 3) ? z * koffStride : 0;
  const int nbx = N >> 8;
  const int q8 = gridDim.x >> 3;  // grids are multiples of 8
  const int gid = blockIdx.x;
  const int lid = (gid & 7) * q8 + (gid >> 3);  // XCD-contiguous logical id (T1)
  const int by = lid / nbx, bx = lid % nbx;
  const int bm = by << 8, bn = bx << 8;
  const int tid = threadIdx.x;
  const int w = tid >> 6, l = tid & 63;
  const int wr = w >> 2, wc = w & 3;
  const int l16 = l & 15, l4 = l >> 4;
  const int NT2 = KC >> 6, NTT = KC >> 5;
  const int srow = (w << 4) + (l >> 2);
  const int scolb = ((l & 3) << 4) ^ (((l >> 3) & 1) << 5) ^ (((l >> 4) & 1) << 4);
  char* ldsb = (char*)lds;

  auto STG = [&](const u16* src, int ldx, int rowBase, int kt, int ldsOffU16) {
    const char* g = (const char*)src + ((size_t)(rowBase + srow) * ldx + kt) * 2 + scolb;
    gload_lds16(g, ldsb + ldsOffU16 * 2 + (w << 10));
  };

  f32x4 acc[8][4] = {};
  u16x8 a[4], b[4];

  auto LDA4 = [&](int bufU16, int mh) {
#pragma unroll
    for (int j = 0; j < 4; ++j) {
      int row = wr * 128 + mh * 64 + j * 16 + l16;
      int off = (row << 5) + (l4 << 3);
      off ^= (((row >> 1) & 1) << 4) | (((row >> 2) & 1) << 3);
      a[j] = *(const u16x8*)(lds + bufU16 + off);
    }
  };
  auto LDB2 = [&](int bufU16, int nh) {
#pragma unroll
    for (int j = 0; j < 2; ++j) {
      int row = wc * 64 + nh * 32 + j * 16 + l16;
      int off = (row << 5) + (l4 << 3);
      off ^= (((row >> 1) & 1) << 4) | (((row >> 2) & 1) << 3);
      b[nh * 2 + j] = *(const u16x8*)(lds + bufU16 + 8192 + off);
    }
  };
  auto MM = [&](int mh, int nh) {
    __builtin_amdgcn_s_setprio(1);
#pragma unroll
    for (int mt = 0; mt < 4; ++mt)
#pragma unroll
      for (int nt = 0; nt < 2; ++nt)
        acc[mh * 4 + mt][nh * 2 + nt] = mfma16(a[mt], b[nh * 2 + nt], acc[mh * 4 + mt][nh * 2 + nt]);
    __builtin_amdgcn_s_setprio(0);
  };

  STG(Ap, lda, bm, koff, 0);
  STG(Ap, lda, bm + 128, koff, 4096);
  STG(Bp, ldb, bn, koff, 8192);
  STG(Bp, ldb, bn + 128, koff, 12288);
  STG(Ap, lda, bm, koff + 32, 16384);
  STG(Ap, lda, bm + 128, koff + 32, 20480);
  asm volatile("s_waitcnt vmcnt(2)" ::: "memory");
  __builtin_amdgcn_sched_barrier(0);
  __builtin_amdgcn_s_barrier();

  for (int it = 0; it < NT2; ++it) {
    const int t1 = 2 * it + 1, t2 = 2 * it + 2, t3 = 2 * it + 3;
    const int k1 = koff + (t1 < NTT ? t1 * 32 : 0);
    const int k2 = koff + (t2 < NTT ? t2 * 32 : 0);
    const int k3 = koff + (t3 < NTT ? t3 * 32 : 0);
    LDA4(0, 0); LDB2(0, 0);
    STG(Bp, ldb, bn, k1, 24576);
    __builtin_amdgcn_s_barrier();
    MM(0, 0);
    __builtin_amdgcn_s_barrier();
    LDB2(0, 1);
    STG(Bp, ldb, bn + 128, k1, 28672);
    __builtin_amdgcn_s_barrier();
    MM(0, 1);
    __builtin_amdgcn_s_barrier();
    LDA4(0, 1);
    __builtin_amdgcn_s_barrier();
    MM(1, 0);
    __builtin_amdgcn_s_barrier();
    STG(Ap, lda, bm, k2, 0);
    STG(Ap, lda, bm + 128, k2, 4096);
    asm volatile("s_waitcnt vmcnt(2)" ::: "memory");
    __builtin_amdgcn_sched_barrier(0);
    __builtin_amdgcn_s_barrier();
    MM(1, 1);
    __builtin_amdgcn_s_barrier();
    LDA4(16384, 0); LDB2(16384, 0);
    STG(Bp, ldb, bn, k2, 8192);
    __builtin_amdgcn_s_barrier();
    MM(0, 0);
    __builtin_amdgcn_s_barrier();
    LDB2(16384, 1);
    STG(Bp, ldb, bn + 128, k2, 12288);
    __builtin_amdgcn_s_barrier();
    MM(0, 1);
    __builtin_amdgcn_s_barrier();
    LDA4(16384, 1);
    __builtin_amdgcn_s_barrier();
    MM(1, 0);
    __builtin_amdgcn_s_barrier();
    STG(Ap, lda, bm, k3, 16384);
    STG(Ap, lda, bm + 128, k3, 20480);
    asm volatile("s_waitcnt vmcnt(2)" ::: "memory");
    __builtin_amdgcn_sched_barrier(0);
    __builtin_amdgcn_s_barrier();
    MM(1, 1);
    __builtin_amdgcn_s_barrier();
  }

#pragma unroll
  for (int i = 0; i < 8; ++i)
#pragma unroll
    for (int j = 0; j < 4; ++j)
#pragma unroll
      for (int r = 0; r < 4; ++r) {
        const int row = bm + wr * 128 + i * 16 + l4 * 4 + r;
        const int col = bn + wc * 64 + j * 16 + l16;
        const size_t idx = (size_t)row * N + col;
        float v = acc[i][j][r];
        if (EPI == 0) {
          ((u16*)outp)[(size_t)z * bStrideO + idx] = f2bf(v);
        } else if (EPI == 1) {
          ((float*)outp)[idx] = v + ((const float*)extra)[idx];
        } else if (EPI == 2) {
          float g = bf2f(((const u16*)extra)[idx]);
          float sig = 1.0f / (1.0f + __expf(-v));
          ((u16*)outp)[idx] = f2bf(g * v * sig);
        } else {
          ((float*)outp)[(size_t)z * M * N + idx] = v;
        }
      }
}

// ---------------- split-K reduce: out = p0+p1+p2+p3 + res ----------------
__global__ __launch_bounds__(256) void reduce4(const float* __restrict__ p, const float* __restrict__ res,
                                               float* __restrict__ out, size_t n) {
  size_t i = ((size_t)blockIdx.x * 256 + threadIdx.x) * 4;
  float4 a = *(const float4*)(p + i);
  float4 b = *(const float4*)(p + n + i);
  float4 c = *(const float4*)(p + 2 * n + i);
  float4 d = *(const float4*)(p + 3 * n + i);
  float4 r = *(const float4*)(res + i);
  float4 o;
  o.x = a.x + b.x + c.x + d.x + r.x;
  o.y = a.y + b.y + c.y + d.y + r.y;
  o.z = a.z + b.z + c.z + d.z + r.z;
  o.w = a.w + b.w + c.w + d.w + r.w;
  *(float4*)(out + i) = o;
}

// ---------------- RoPE ----------------
__global__ __launch_bounds__(256) void rope_table(float2* __restrict__ tab) {
  int idx = blockIdx.x * 256 + threadIdx.x;  // S*32 = 65536
  int pos = idx >> 5, i = idx & 31;
  float inv = __expf(-(float)(2 * i) * (9.210340371976184f / 64.0f));
  float a = (float)pos * inv;
  float s, c;
  __sincosf(a, &s, &c);
  tab[idx] = make_float2(c, s);
}

__global__ __launch_bounds__(256) void rope_apply(u16* __restrict__ q, u16* __restrict__ k,
                                                  const float2* __restrict__ tab) {
  int idx = blockIdx.x * 256 + threadIdx.x;  // S*H*32 = 2M
  int i = idx & 31;
  int hh = (idx >> 5) & 31;
  int pos = idx >> 10;
  float2 cs = tab[(pos << 5) + i];
  size_t base = (size_t)pos * 2048 + hh * 64 + i;
  float a0 = bf2f(q[base]), a1 = bf2f(q[base + 32]);
  q[base] = f2bf(a0 * cs.x - a1 * cs.y);
  q[base + 32] = f2bf(a1 * cs.x + a0 * cs.y);
  float b0 = bf2f(k[base]), b1 = bf2f(k[base + 32]);
  k[base] = f2bf(b0 * cs.x - b1 * cs.y);
  k[base + 32] = f2bf(b1 * cs.x + b0 * cs.y);
}

// ---------------- V transpose: v[S][D] -> vT[h][d][S] ----------------
__global__ __launch_bounds__(256) void transpose_v(const u16* __restrict__ v, u16* __restrict__ vt) {
  __shared__ u16 t[64][72];
  const int t0 = blockIdx.x * 64, h = blockIdx.y, tid = threadIdx.x;
  {
    const int r = tid >> 3, c8 = (tid & 7) * 8;
#pragma unroll
    for (int j = 0; j < 2; ++j) {
      u16x8 val = *(const u16x8*)(v + (size_t)(t0 + r + 32 * j) * 2048 + h * 64 + c8);
      *(u16x8*)&t[r + 32 * j][c8] = val;
    }
  }
  __syncthreads();
  const int d = tid >> 2, q = (tid & 3) * 16;
  u16x8 lo, hi;
#pragma unroll
  for (int e = 0; e < 8; ++e) lo[e] = t[q + e][d];
#pragma unroll
  for (int e = 0; e < 8; ++e) hi[e] = t[q + 8 + e][d];
  *(u16x8*)(vt + (size_t)(h * 64 + d) * 2048 + t0 + q) = lo;
  *(u16x8*)(vt + (size_t)(h * 64 + d) * 2048 + t0 + q + 8) = hi;
}

// ---------------- Flash attention v4: block-shared LDS K/V staging ----------------
// grid (S/128, H) remapped in-kernel so each head's 16 q-blocks share one XCD.
// 4 waves x 32 q-rows. K/V tiles staged ONCE per block into swizzled LDS,
// double-buffered: STAGE(t+1) -> TILE(t) -> __syncthreads() (drain+barrier).
__global__ __launch_bounds__(256) void flash_attn(const u16* __restrict__ qb, const u16* __restrict__ kb,
                                                  const u16* __restrict__ vt, u16* __restrict__ ob) {
  const int id = blockIdx.x + (blockIdx.y << 4);
  const int h = ((id & 7) << 2) | ((id >> 3) & 3);  // 4 heads per XCD -> K/V L2-resident
  const int q0 = (id >> 5) << 7;
  const int w = threadIdx.x >> 6, l = threadIdx.x & 63;
  const int l16 = l & 15, l4 = l >> 4;
  const float C = 0.125f * 1.4426950408889634f;  // exp2-domain scale
  __shared__ u16 KV[2][2][64 * 64];  // [buf][K|V][row][64], XOR-swizzled chunks
  __shared__ u16 P[4][32][72];
  // staging lane constants: linear LDS dest, inverse-swizzled global source chunk
  const int srow8 = l >> 3;                 // row within 8-row group
  const int schunk = (l & 7) ^ srow8;       // pre-swizzled 16B-chunk index

  auto STAGE = [&](int t0, int buf) {
#pragma unroll
    for (int j = 0; j < 2; ++j) {
      const int rg = w * 16 + j * 8;        // row-group base (wave-uniform)
      const int row = rg + srow8;
      gload_lds16(kb + (size_t)(t0 + row) * 2048 + h * 64 + schunk * 8, &KV[buf][0][rg * 64]);
      gload_lds16(vt + (size_t)(h * 64 + row) * 2048 + t0 + schunk * 8, &KV[buf][1][rg * 64]);
    }
  };

  u16x8 qf[2][2];
#pragma unroll
  for (int rt = 0; rt < 2; ++rt)
#pragma unroll
    for (int kh = 0; kh < 2; ++kh)
      qf[rt][kh] = *(const u16x8*)(qb + (size_t)(q0 + w * 32 + rt * 16 + l16) * 2048 + h * 64 + kh * 32 + l4 * 8);
  float mrun[8], lrun[8];
  f32x4 oacc[2][4] = {};
#pragma unroll
  for (int i = 0; i < 8; ++i) { mrun[i] = -1e30f; lrun[i] = 0.f; }

  auto TILE = [&](int t0, int buf) {
    f32x4 sacc[2][4] = {};
#pragma unroll
    for (int kh = 0; kh < 2; ++kh)
#pragma unroll
      for (int tt = 0; tt < 4; ++tt) {
        const int row = tt * 16 + l16;
        const int ch = (kh * 4 + l4) ^ (row & 7);
        u16x8 kf = *(const u16x8*)&KV[buf][0][row * 64 + ch * 8];
#pragma unroll
        for (int rt = 0; rt < 2; ++rt)
          sacc[rt][tt] = mfma16(qf[rt][kh], kf, sacc[rt][tt]);
      }
    float v[8][4], mx[8];
#pragma unroll
    for (int i = 0; i < 8; ++i) {
      const int rt = i >> 2, r = i & 3;
#pragma unroll
      for (int tt = 0; tt < 4; ++tt) v[i][tt] = sacc[rt][tt][r] * C;
      mx[i] = fmaxf(fmaxf(v[i][0], v[i][1]), fmaxf(v[i][2], v[i][3]));
    }
#pragma unroll
    for (int s = 1; s <= 8; s <<= 1)
#pragma unroll
      for (int i = 0; i < 8; ++i) mx[i] = fmaxf(mx[i], __shfl_xor(mx[i], s));
    float sfac[8], ps[8];
#pragma unroll
    for (int i = 0; i < 8; ++i) {
      float mnew = fmaxf(mrun[i], mx[i]);
      sfac[i] = exp2f(mrun[i] - mnew);
      mrun[i] = mnew;
      float p0 = exp2f(v[i][0] - mnew), p1 = exp2f(v[i][1] - mnew);
      float p2 = exp2f(v[i][2] - mnew), p3 = exp2f(v[i][3] - mnew);
      const int pr = (i >> 2) * 16 + l4 * 4 + (i & 3);
      P[w][pr][l16] = f2bf(p0);
      P[w][pr][16 + l16] = f2bf(p1);
      P[w][pr][32 + l16] = f2bf(p2);
      P[w][pr][48 + l16] = f2bf(p3);
      ps[i] = (p0 + p1) + (p2 + p3);
    }
#pragma unroll
    for (int s = 1; s <= 8; s <<= 1)
#pragma unroll
      for (int i = 0; i < 8; ++i) ps[i] += __shfl_xor(ps[i], s);
#pragma unroll
    for (int i = 0; i < 8; ++i) lrun[i] = lrun[i] * sfac[i] + ps[i];
#pragma unroll
    for (int rt = 0; rt < 2; ++rt)
#pragma unroll
      for (int nt = 0; nt < 4; ++nt)
#pragma unroll
        for (int r = 0; r < 4; ++r)
          oacc[rt][nt][r] *= sfac[rt * 4 + r];
#pragma unroll
    for (int ks = 0; ks < 2; ++ks) {
      u16x8 pf[2];
#pragma unroll
      for (int rt = 0; rt < 2; ++rt)
        pf[rt] = *(const u16x8*)&P[w][rt * 16 + l16][ks * 32 + l4 * 8];
#pragma unroll
      for (int nt = 0; nt < 4; ++nt) {
        const int row = nt * 16 + l16;
        const int ch = (ks * 4 + l4) ^ (row & 7);
        u16x8 vf = *(const u16x8*)&KV[buf][1][row * 64 + ch * 8];
#pragma unroll
        for (int rt = 0; rt < 2; ++rt)
          oacc[rt][nt] = mfma16(pf[rt], vf, oacc[rt][nt]);
      }
    }
  };

  STAGE(0, 0);
  __syncthreads();
  int buf = 0;
  for (int t = 0; t < 32; ++t) {
    if (t < 31) STAGE((t + 1) * 64, buf ^ 1);  // async loads issue before compute
    TILE(t * 64, buf);
    __syncthreads();  // drains vmcnt(0)+lgkmcnt(0) then s_barrier: staged tile ready
    buf ^= 1;
  }
#pragma unroll
  for (int rt = 0; rt < 2; ++rt)
#pragma unroll
    for (int r = 0; r < 4; ++r) {
      float inv = 1.0f / lrun[rt * 4 + r];
#pragma unroll
      for (int nt = 0; nt < 4; ++nt)
        ob[(size_t)(q0 + w * 32 + rt * 16 + l4 * 4 + r) * 2048 + h * 64 + nt * 16 + l16] =
            f2bf(oacc[rt][nt][r] * inv);
    }
}

extern "C" void kernel_launch(void* const* d_in, const int* in_sizes, int n_in,
                              void* d_out, int out_size, void* d_ws, size_t ws_size,
                              hipStream_t stream) {
  const float* x    = (const float*)d_in[0];
  const float* w_in = (const float*)d_in[1];
  const float* wq   = (const float*)d_in[2];
  const float* wk   = (const float*)d_in[3];
  const float* wv   = (const float*)d_in[4];
  const float* wo   = (const float*)d_in[5];
  const float* w_pn = (const float*)d_in[6];
  const float* wg   = (const float*)d_in[7];
  const float* wu   = (const float*)d_in[8];
  const float* wd   = (const float*)d_in[9];
  float* out = (float*)d_out;
  char* ws = (char*)d_ws;
  const size_t MB = 1ull << 20;
  const int S = 2048, D = 2048, FF = 8192;

  u16* W_QKV = (u16*)(ws);               // 24 MB
  u16* W_O   = (u16*)(ws + 24 * MB);     // 8 MB
  u16* W_G   = (u16*)(ws + 32 * MB);     // 32 MB
  u16* W_U   = (u16*)(ws + 64 * MB);     // 32 MB
  u16* W_D   = (u16*)(ws + 96 * MB);     // 32 MB
  u16* HB    = (u16*)(ws + 128 * MB);    // 8 MB
  u16* QKVB  = (u16*)(ws + 136 * MB);    // 24 MB (q,k,v)
  u16* VT    = (u16*)(ws + 160 * MB);    // 8 MB
  u16* ATTNB = (u16*)(ws + 168 * MB);    // 8 MB
  float* X1  = (float*)(ws + 176 * MB);  // 16 MB
  u16* H2B   = (u16*)(ws + 192 * MB);    // 8 MB
  float2* RT = (float2*)(ws + 200 * MB); // 0.5 MB
  u16* GATEB = (u16*)(ws);               // 32 MB, overlays W_QKV+W_O (dead after O-proj)
  u16* PRODB = (u16*)(ws + 136 * MB);    // 32 MB, overlays QKVB+VT (dead after attention)
  float* DP  = (float*)(ws);             // 64 MB down-proj partials
  float* OP  = (float*)(ws + 208 * MB);  // 64 MB O-proj partials (only if ws permits)
  const bool splitO = ws_size >= 272 * MB;

  rope_table<<<65536 / 256, 256, 0, stream>>>(RT);
  cast_w<<<(D * D) / 2048, 256, 0, stream>>>(wq, W_QKV);
  cast_w<<<(D * D) / 2048, 256, 0, stream>>>(wk, W_QKV + (size_t)D * D);
  cast_w<<<(D * D) / 2048, 256, 0, stream>>>(wv, W_QKV + 2 * (size_t)D * D);
  cast_w<<<(D * D) / 2048, 256, 0, stream>>>(wo, W_O);
  cast_w<<<(FF * D) / 2048, 256, 0, stream>>>(wg, W_G);
  cast_w<<<(FF * D) / 2048, 256, 0, stream>>>(wu, W_U);
  cast_w<<<(FF * D) / 2048, 256, 0, stream>>>(wd, W_D);
  rmsnorm_cast<<<S, 256, 0, stream>>>(x, w_in, HB);
  gemm8<0><<<dim3(64, 1, 3), 512, 0, stream>>>(HB, W_QKV, QKVB, nullptr, S, D, D, D, D, 0,
                                               (long long)D * D, (long long)S * D);
  rope_apply<<<(S * 32 * 32) / 256, 256, 0, stream>>>(QKVB, QKVB + (size_t)S * D, RT);
  transpose_v<<<dim3(S / 64, 32), 256, 0, stream>>>(QKVB + 2 * (size_t)S * D, VT);
  flash_attn<<<dim3(S / 128, 32), 256, 0, stream>>>(QKVB, QKVB + (size_t)S * D, VT, ATTNB);
  if (splitO) {
    gemm8<3><<<dim3(64, 1, 4), 512, 0, stream>>>(ATTNB, W_O, OP, nullptr, S, D, 512, D, D, 512, 0, 0);
    reduce4<<<(S * D) / 1024, 256, 0, stream>>>(OP, x, X1, (size_t)S * D);
  } else {
    gemm8<1><<<dim3(64, 1, 1), 512, 0, stream>>>(ATTNB, W_O, X1, x, S, D, D, D, D, 0, 0, 0);
  }
  rmsnorm_cast<<<S, 256, 0, stream>>>(X1, w_pn, H2B);
  gemm8<0><<<dim3(256, 1, 1), 512, 0, stream>>>(H2B, W_G, GATEB, nullptr, S, FF, D, D, D, 0, 0, 0);
  gemm8<2><<<dim3(256, 1, 1), 512, 0, stream>>>(H2B, W_U, PRODB, GATEB, S, FF, D, D, D, 0, 0, 0);
  gemm8<3><<<dim3(64, 1, 4), 512, 0, stream>>>(PRODB, W_D, DP, nullptr, S, D, 2048, FF, FF, 2048, 0, 0);
  reduce4<<<(S * D) / 1024, 256, 0, stream>>>(DP, X1, out, (size_t)S * D);
  (void)in_sizes; (void)n_in; (void)out_size;
}

// Round 7
// 560.296 us; speedup vs baseline: 1.2873x; 1.0583x over previous
//
#include <hip/hip_runtime.h>

typedef unsigned short u16;
typedef __attribute__((ext_vector_type(8))) unsigned short u16x8;
typedef __attribute__((ext_vector_type(8))) __bf16 bf16x8;
typedef __attribute__((ext_vector_type(4))) float f32x4;

#define DEV __device__ __forceinline__

DEV u16 f2bf(float f) {
  unsigned u = __builtin_bit_cast(unsigned, f);
  u += 0x7FFFu + ((u >> 16) & 1u);
  return (u16)(u >> 16);
}
DEV float bf2f(u16 h) {
  unsigned u = ((unsigned)h) << 16;
  return __builtin_bit_cast(float, u);
}
DEV f32x4 mfma16(u16x8 a, u16x8 b, f32x4 c) {
  return __builtin_amdgcn_mfma_f32_16x16x32_bf16(
      __builtin_bit_cast(bf16x8, a), __builtin_bit_cast(bf16x8, b), c, 0, 0, 0);
}
DEV void gload_lds16(const void* g, void* l) {
  __builtin_amdgcn_global_load_lds(
      (const __attribute__((address_space(1))) void*)g,
      (__attribute__((address_space(3))) void*)l, 16, 0, 0);
}

// ---------------- weight cast fp32 -> bf16 ----------------
__global__ __launch_bounds__(256) void cast_w(const float* __restrict__ in, u16* __restrict__ out) {
  size_t i = ((size_t)blockIdx.x * 256 + threadIdx.x) * 8;
  float4 a = *(const float4*)(in + i);
  float4 b = *(const float4*)(in + i + 4);
  u16x8 o;
  o[0] = f2bf(a.x); o[1] = f2bf(a.y); o[2] = f2bf(a.z); o[3] = f2bf(a.w);
  o[4] = f2bf(b.x); o[5] = f2bf(b.y); o[6] = f2bf(b.z); o[7] = f2bf(b.w);
  *(u16x8*)(out + i) = o;
}

// ---------------- RMSNorm (fp32 in) -> bf16 out ----------------
__global__ __launch_bounds__(256) void rmsnorm_cast(const float* __restrict__ x, const float* __restrict__ w,
                                                    u16* __restrict__ out) {
  const int row = blockIdx.x, tid = threadIdx.x;
  const float* xr = x + (size_t)row * 2048;
  float4 a = *(const float4*)(xr + tid * 8);
  float4 b = *(const float4*)(xr + tid * 8 + 4);
  float ss = a.x * a.x + a.y * a.y + a.z * a.z + a.w * a.w +
             b.x * b.x + b.y * b.y + b.z * b.z + b.w * b.w;
#pragma unroll
  for (int off = 32; off; off >>= 1) ss += __shfl_xor(ss, off);
  __shared__ float part[4];
  if ((tid & 63) == 0) part[tid >> 6] = ss;
  __syncthreads();
  float tot = part[0] + part[1] + part[2] + part[3];
  float r = rsqrtf(tot * (1.0f / 2048.0f) + 1e-5f);
  float4 wa = *(const float4*)(w + tid * 8);
  float4 wb = *(const float4*)(w + tid * 8 + 4);
  u16x8 o;
  o[0] = f2bf(a.x * r * wa.x); o[1] = f2bf(a.y * r * wa.y);
  o[2] = f2bf(a.z * r * wa.z); o[3] = f2bf(a.w * r * wa.w);
  o[4] = f2bf(b.x * r * wb.x); o[5] = f2bf(b.y * r * wb.y);
  o[6] = f2bf(b.z * r * wb.z); o[7] = f2bf(b.w * r * wb.w);
  *(u16x8*)(out + (size_t)row * 2048 + tid * 8) = o;
}

// ============ 256x256-tile, 8-wave, 8-phase NT GEMM (counted vmcnt) ============
template <int EPI>
__global__ __launch_bounds__(512) void gemm8(const u16* __restrict__ Ag, const u16* __restrict__ Bg,
                                             void* __restrict__ outp, const void* __restrict__ extra,
                                             int M, int N, int KC, int lda, int ldb, int koffStride,
                                             long long bStrideB, long long bStrideO) {
  __shared__ u16 lds[32768];  // 64 KiB
  const int z = blockIdx.z;
  const u16* Ap = Ag;
  const u16* Bp = Bg + (EPI == 0 ? (size_t)z * bStrideB : (size_t)0);
  const int koff = (EPI == 3) ? z * koffStride : 0;
  const int nbx = N >> 8;
  const int q8 = gridDim.x >> 3;  // grids are multiples of 8
  const int gid = blockIdx.x;
  const int lid = (gid & 7) * q8 + (gid >> 3);  // XCD-contiguous logical id (T1)
  const int by = lid / nbx, bx = lid % nbx;
  const int bm = by << 8, bn = bx << 8;
  const int tid = threadIdx.x;
  const int w = tid >> 6, l = tid & 63;
  const int wr = w >> 2, wc = w & 3;
  const int l16 = l & 15, l4 = l >> 4;
  const int NT2 = KC >> 6, NTT = KC >> 5;
  const int srow = (w << 4) + (l >> 2);
  const int scolb = ((l & 3) << 4) ^ (((l >> 3) & 1) << 5) ^ (((l >> 4) & 1) << 4);
  char* ldsb = (char*)lds;

  auto STG = [&](const u16* src, int ldx, int rowBase, int kt, int ldsOffU16) {
    const char* g = (const char*)src + ((size_t)(rowBase + srow) * ldx + kt) * 2 + scolb;
    gload_lds16(g, ldsb + ldsOffU16 * 2 + (w << 10));
  };

  f32x4 acc[8][4] = {};
  u16x8 a[4], b[4];

  auto LDA4 = [&](int bufU16, int mh) {
#pragma unroll
    for (int j = 0; j < 4; ++j) {
      int row = wr * 128 + mh * 64 + j * 16 + l16;
      int off = (row << 5) + (l4 << 3);
      off ^= (((row >> 1) & 1) << 4) | (((row >> 2) & 1) << 3);
      a[j] = *(const u16x8*)(lds + bufU16 + off);
    }
  };
  auto LDB2 = [&](int bufU16, int nh) {
#pragma unroll
    for (int j = 0; j < 2; ++j) {
      int row = wc * 64 + nh * 32 + j * 16 + l16;
      int off = (row << 5) + (l4 << 3);
      off ^= (((row >> 1) & 1) << 4) | (((row >> 2) & 1) << 3);
      b[nh * 2 + j] = *(const u16x8*)(lds + bufU16 + 8192 + off);
    }
  };
  auto MM = [&](int mh, int nh) {
    __builtin_amdgcn_s_setprio(1);
#pragma unroll
    for (int mt = 0; mt < 4; ++mt)
#pragma unroll
      for (int nt = 0; nt < 2; ++nt)
        acc[mh * 4 + mt][nh * 2 + nt] = mfma16(a[mt], b[nh * 2 + nt], acc[mh * 4 + mt][nh * 2 + nt]);
    __builtin_amdgcn_s_setprio(0);
  };

  STG(Ap, lda, bm, koff, 0);
  STG(Ap, lda, bm + 128, koff, 4096);
  STG(Bp, ldb, bn, koff, 8192);
  STG(Bp, ldb, bn + 128, koff, 12288);
  STG(Ap, lda, bm, koff + 32, 16384);
  STG(Ap, lda, bm + 128, koff + 32, 20480);
  asm volatile("s_waitcnt vmcnt(2)" ::: "memory");
  __builtin_amdgcn_sched_barrier(0);
  __builtin_amdgcn_s_barrier();

  for (int it = 0; it < NT2; ++it) {
    const int t1 = 2 * it + 1, t2 = 2 * it + 2, t3 = 2 * it + 3;
    const int k1 = koff + (t1 < NTT ? t1 * 32 : 0);
    const int k2 = koff + (t2 < NTT ? t2 * 32 : 0);
    const int k3 = koff + (t3 < NTT ? t3 * 32 : 0);
    LDA4(0, 0); LDB2(0, 0);
    STG(Bp, ldb, bn, k1, 24576);
    __builtin_amdgcn_s_barrier();
    MM(0, 0);
    __builtin_amdgcn_s_barrier();
    LDB2(0, 1);
    STG(Bp, ldb, bn + 128, k1, 28672);
    __builtin_amdgcn_s_barrier();
    MM(0, 1);
    __builtin_amdgcn_s_barrier();
    LDA4(0, 1);
    __builtin_amdgcn_s_barrier();
    MM(1, 0);
    __builtin_amdgcn_s_barrier();
    STG(Ap, lda, bm, k2, 0);
    STG(Ap, lda, bm + 128, k2, 4096);
    asm volatile("s_waitcnt vmcnt(2)" ::: "memory");
    __builtin_amdgcn_sched_barrier(0);
    __builtin_amdgcn_s_barrier();
    MM(1, 1);
    __builtin_amdgcn_s_barrier();
    LDA4(16384, 0); LDB2(16384, 0);
    STG(Bp, ldb, bn, k2, 8192);
    __builtin_amdgcn_s_barrier();
    MM(0, 0);
    __builtin_amdgcn_s_barrier();
    LDB2(16384, 1);
    STG(Bp, ldb, bn + 128, k2, 12288);
    __builtin_amdgcn_s_barrier();
    MM(0, 1);
    __builtin_amdgcn_s_barrier();
    LDA4(16384, 1);
    __builtin_amdgcn_s_barrier();
    MM(1, 0);
    __builtin_amdgcn_s_barrier();
    STG(Ap, lda, bm, k3, 16384);
    STG(Ap, lda, bm + 128, k3, 20480);
    asm volatile("s_waitcnt vmcnt(2)" ::: "memory");
    __builtin_amdgcn_sched_barrier(0);
    __builtin_amdgcn_s_barrier();
    MM(1, 1);
    __builtin_amdgcn_s_barrier();
  }

#pragma unroll
  for (int i = 0; i < 8; ++i)
#pragma unroll
    for (int j = 0; j < 4; ++j)
#pragma unroll
      for (int r = 0; r < 4; ++r) {
        const int row = bm + wr * 128 + i * 16 + l4 * 4 + r;
        const int col = bn + wc * 64 + j * 16 + l16;
        const size_t idx = (size_t)row * N + col;
        float v = acc[i][j][r];
        if (EPI == 0) {
          ((u16*)outp)[(size_t)z * bStrideO + idx] = f2bf(v);
        } else if (EPI == 1) {
          ((float*)outp)[idx] = v + ((const float*)extra)[idx];
        } else if (EPI == 2) {
          float g = bf2f(((const u16*)extra)[idx]);
          float sig = 1.0f / (1.0f + __expf(-v));
          ((u16*)outp)[idx] = f2bf(g * v * sig);
        } else {
          ((float*)outp)[(size_t)z * M * N + idx] = v;
        }
      }
}

// ---------------- split-K reduce: out = p0+p1+p2+p3 + res ----------------
__global__ __launch_bounds__(256) void reduce4(const float* __restrict__ p, const float* __restrict__ res,
                                               float* __restrict__ out, size_t n) {
  size_t i = ((size_t)blockIdx.x * 256 + threadIdx.x) * 4;
  float4 a = *(const float4*)(p + i);
  float4 b = *(const float4*)(p + n + i);
  float4 c = *(const float4*)(p + 2 * n + i);
  float4 d = *(const float4*)(p + 3 * n + i);
  float4 r = *(const float4*)(res + i);
  float4 o;
  o.x = a.x + b.x + c.x + d.x + r.x;
  o.y = a.y + b.y + c.y + d.y + r.y;
  o.z = a.z + b.z + c.z + d.z + r.z;
  o.w = a.w + b.w + c.w + d.w + r.w;
  *(float4*)(out + i) = o;
}

// ---------------- RoPE ----------------
__global__ __launch_bounds__(256) void rope_table(float2* __restrict__ tab) {
  int idx = blockIdx.x * 256 + threadIdx.x;  // S*32 = 65536
  int pos = idx >> 5, i = idx & 31;
  float inv = __expf(-(float)(2 * i) * (9.210340371976184f / 64.0f));
  float a = (float)pos * inv;
  float s, c;
  __sincosf(a, &s, &c);
  tab[idx] = make_float2(c, s);
}

__global__ __launch_bounds__(256) void rope_apply(u16* __restrict__ q, u16* __restrict__ k,
                                                  const float2* __restrict__ tab) {
  int idx = blockIdx.x * 256 + threadIdx.x;  // S*H*32 = 2M
  int i = idx & 31;
  int hh = (idx >> 5) & 31;
  int pos = idx >> 10;
  float2 cs = tab[(pos << 5) + i];
  size_t base = (size_t)pos * 2048 + hh * 64 + i;
  float a0 = bf2f(q[base]), a1 = bf2f(q[base + 32]);
  q[base] = f2bf(a0 * cs.x - a1 * cs.y);
  q[base + 32] = f2bf(a1 * cs.x + a0 * cs.y);
  float b0 = bf2f(k[base]), b1 = bf2f(k[base + 32]);
  k[base] = f2bf(b0 * cs.x - b1 * cs.y);
  k[base + 32] = f2bf(b1 * cs.x + b0 * cs.y);
}

// ---------------- V transpose: v[S][D] -> vT[h][d][S] ----------------
__global__ __launch_bounds__(256) void transpose_v(const u16* __restrict__ v, u16* __restrict__ vt) {
  __shared__ u16 t[64][72];
  const int t0 = blockIdx.x * 64, h = blockIdx.y, tid = threadIdx.x;
  {
    const int r = tid >> 3, c8 = (tid & 7) * 8;
#pragma unroll
    for (int j = 0; j < 2; ++j) {
      u16x8 val = *(const u16x8*)(v + (size_t)(t0 + r + 32 * j) * 2048 + h * 64 + c8);
      *(u16x8*)&t[r + 32 * j][c8] = val;
    }
  }
  __syncthreads();
  const int d = tid >> 2, q = (tid & 3) * 16;
  u16x8 lo, hi;
#pragma unroll
  for (int e = 0; e < 8; ++e) lo[e] = t[q + e][d];
#pragma unroll
  for (int e = 0; e < 8; ++e) hi[e] = t[q + 8 + e][d];
  *(u16x8*)(vt + (size_t)(h * 64 + d) * 2048 + t0 + q) = lo;
  *(u16x8*)(vt + (size_t)(h * 64 + d) * 2048 + t0 + q + 8) = hi;
}

// ---------------- Flash attention v5 ----------------
// v4 structure (block-shared swizzled LDS K/V staging, head-grouped XCD remap)
// + Q pre-scaled by 0.125*log2e (exp2 domain, no per-tile scale mul)
// + per-lane partial row-sum; single cross-lane sum reduce AFTER the loop
// + defer-max (T13): skip max-reduce/rescale when no lane's partial max
//   exceeds running max + 11.54 (= 8 nats in exp2 domain)
__global__ __launch_bounds__(256) void flash_attn(const u16* __restrict__ qb, const u16* __restrict__ kb,
                                                  const u16* __restrict__ vt, u16* __restrict__ ob) {
  const int id = blockIdx.x + (blockIdx.y << 4);
  const int h = ((id & 7) << 2) | ((id >> 3) & 3);  // 4 heads per XCD -> K/V L2-resident
  const int q0 = (id >> 5) << 7;
  const int w = threadIdx.x >> 6, l = threadIdx.x & 63;
  const int l16 = l & 15, l4 = l >> 4;
  const float C = 0.125f * 1.4426950408889634f;  // folded into Q
  const float THR = 11.541560327111708f;         // 8 nats in exp2 domain
  __shared__ u16 KV[2][2][64 * 64];  // [buf][K|V][row][64], XOR-swizzled chunks
  __shared__ u16 P[4][32][72];
  const int srow8 = l >> 3;
  const int schunk = (l & 7) ^ srow8;

  auto STAGE = [&](int t0, int buf) {
#pragma unroll
    for (int j = 0; j < 2; ++j) {
      const int rg = w * 16 + j * 8;
      const int row = rg + srow8;
      gload_lds16(kb + (size_t)(t0 + row) * 2048 + h * 64 + schunk * 8, &KV[buf][0][rg * 64]);
      gload_lds16(vt + (size_t)(h * 64 + row) * 2048 + t0 + schunk * 8, &KV[buf][1][rg * 64]);
    }
  };

  u16x8 qf[2][2];
#pragma unroll
  for (int rt = 0; rt < 2; ++rt)
#pragma unroll
    for (int kh = 0; kh < 2; ++kh) {
      u16x8 q = *(const u16x8*)(qb + (size_t)(q0 + w * 32 + rt * 16 + l16) * 2048 + h * 64 + kh * 32 + l4 * 8);
#pragma unroll
      for (int e = 0; e < 8; ++e) q[e] = f2bf(bf2f(q[e]) * C);
      qf[rt][kh] = q;
    }
  float mrun[8], lrun[8];
  f32x4 oacc[2][4] = {};
#pragma unroll
  for (int i = 0; i < 8; ++i) { mrun[i] = -1e30f; lrun[i] = 0.f; }

  auto TILE = [&](int t0, int buf) {
    f32x4 sacc[2][4] = {};
#pragma unroll
    for (int kh = 0; kh < 2; ++kh)
#pragma unroll
      for (int tt = 0; tt < 4; ++tt) {
        const int row = tt * 16 + l16;
        const int ch = (kh * 4 + l4) ^ (row & 7);
        u16x8 kf = *(const u16x8*)&KV[buf][0][row * 64 + ch * 8];
#pragma unroll
        for (int rt = 0; rt < 2; ++rt)
          sacc[rt][tt] = mfma16(qf[rt][kh], kf, sacc[rt][tt]);
      }
    // per-lane partial max check (defer-max)
    float pmax[8];
    int ok = 1;
#pragma unroll
    for (int i = 0; i < 8; ++i) {
      const int rt = i >> 2, r = i & 3;
      pmax[i] = fmaxf(fmaxf(sacc[rt][0][r], sacc[rt][1][r]), fmaxf(sacc[rt][2][r], sacc[rt][3][r]));
      ok &= (pmax[i] <= mrun[i] + THR) ? 1 : 0;
    }
    if (!__all(ok)) {
      // full cross-lane max reduce + rescale
      float mx[8];
#pragma unroll
      for (int i = 0; i < 8; ++i) mx[i] = pmax[i];
#pragma unroll
      for (int s = 1; s <= 8; s <<= 1)
#pragma unroll
        for (int i = 0; i < 8; ++i) mx[i] = fmaxf(mx[i], __shfl_xor(mx[i], s));
      float sfac[8];
#pragma unroll
      for (int i = 0; i < 8; ++i) {
        float mnew = fmaxf(mrun[i], mx[i]);
        sfac[i] = exp2f(mrun[i] - mnew);
        mrun[i] = mnew;
        lrun[i] *= sfac[i];
      }
#pragma unroll
      for (int rt = 0; rt < 2; ++rt)
#pragma unroll
        for (int nt = 0; nt < 4; ++nt)
#pragma unroll
          for (int r = 0; r < 4; ++r)
            oacc[rt][nt][r] *= sfac[rt * 4 + r];
    }
    // P = exp2(S - mrun), per-lane partial row-sum into lrun
#pragma unroll
    for (int i = 0; i < 8; ++i) {
      const int rt = i >> 2, r = i & 3;
      float p0 = exp2f(sacc[rt][0][r] - mrun[i]);
      float p1 = exp2f(sacc[rt][1][r] - mrun[i]);
      float p2 = exp2f(sacc[rt][2][r] - mrun[i]);
      float p3 = exp2f(sacc[rt][3][r] - mrun[i]);
      const int pr = rt * 16 + l4 * 4 + r;
      P[w][pr][l16] = f2bf(p0);
      P[w][pr][16 + l16] = f2bf(p1);
      P[w][pr][32 + l16] = f2bf(p2);
      P[w][pr][48 + l16] = f2bf(p3);
      lrun[i] += (p0 + p1) + (p2 + p3);
    }
    // PV
#pragma unroll
    for (int ks = 0; ks < 2; ++ks) {
      u16x8 pf[2];
#pragma unroll
      for (int rt = 0; rt < 2; ++rt)
        pf[rt] = *(const u16x8*)&P[w][rt * 16 + l16][ks * 32 + l4 * 8];
#pragma unroll
      for (int nt = 0; nt < 4; ++nt) {
        const int row = nt * 16 + l16;
        const int ch = (ks * 4 + l4) ^ (row & 7);
        u16x8 vf = *(const u16x8*)&KV[buf][1][row * 64 + ch * 8];
#pragma unroll
        for (int rt = 0; rt < 2; ++rt)
          oacc[rt][nt] = mfma16(pf[rt], vf, oacc[rt][nt]);
      }
    }
  };

  STAGE(0, 0);
  __syncthreads();
  int buf = 0;
  for (int t = 0; t < 32; ++t) {
    if (t < 31) STAGE((t + 1) * 64, buf ^ 1);
    TILE(t * 64, buf);
    __syncthreads();
    buf ^= 1;
  }
  // single deferred cross-lane sum reduce
#pragma unroll
  for (int s = 1; s <= 8; s <<= 1)
#pragma unroll
    for (int i = 0; i < 8; ++i) lrun[i] += __shfl_xor(lrun[i], s);
#pragma unroll
  for (int rt = 0; rt < 2; ++rt)
#pragma unroll
    for (int r = 0; r < 4; ++r) {
      float inv = 1.0f / lrun[rt * 4 + r];
#pragma unroll
      for (int nt = 0; nt < 4; ++nt)
        ob[(size_t)(q0 + w * 32 + rt * 16 + l4 * 4 + r) * 2048 + h * 64 + nt * 16 + l16] =
            f2bf(oacc[rt][nt][r] * inv);
    }
}

extern "C" void kernel_launch(void* const* d_in, const int* in_sizes, int n_in,
                              void* d_out, int out_size, void* d_ws, size_t ws_size,
                              hipStream_t stream) {
  const float* x    = (const float*)d_in[0];
  const float* w_in = (const float*)d_in[1];
  const float* wq   = (const float*)d_in[2];
  const float* wk   = (const float*)d_in[3];
  const float* wv   = (const float*)d_in[4];
  const float* wo   = (const float*)d_in[5];
  const float* w_pn = (const float*)d_in[6];
  const float* wg   = (const float*)d_in[7];
  const float* wu   = (const float*)d_in[8];
  const float* wd   = (const float*)d_in[9];
  float* out = (float*)d_out;
  char* ws = (char*)d_ws;
  const size_t MB = 1ull << 20;
  const int S = 2048, D = 2048, FF = 8192;

  u16* W_QKV = (u16*)(ws);               // 24 MB
  u16* W_O   = (u16*)(ws + 24 * MB);     // 8 MB
  u16* W_G   = (u16*)(ws + 32 * MB);     // 32 MB
  u16* W_U   = (u16*)(ws + 64 * MB);     // 32 MB
  u16* W_D   = (u16*)(ws + 96 * MB);     // 32 MB
  u16* HB    = (u16*)(ws + 128 * MB);    // 8 MB
  u16* QKVB  = (u16*)(ws + 136 * MB);    // 24 MB (q,k,v)
  u16* VT    = (u16*)(ws + 160 * MB);    // 8 MB
  u16* ATTNB = (u16*)(ws + 168 * MB);    // 8 MB
  float* X1  = (float*)(ws + 176 * MB);  // 16 MB
  u16* H2B   = (u16*)(ws + 192 * MB);    // 8 MB
  float2* RT = (float2*)(ws + 200 * MB); // 0.5 MB
  u16* GATEB = (u16*)(ws);               // 32 MB, overlays W_QKV+W_O (dead after O-proj)
  u16* PRODB = (u16*)(ws + 136 * MB);    // 32 MB, overlays QKVB+VT (dead after attention)
  float* DP  = (float*)(ws);             // 64 MB down-proj partials
  float* OP  = (float*)(ws + 208 * MB);  // 64 MB O-proj partials (only if ws permits)
  const bool splitO = ws_size >= 272 * MB;

  rope_table<<<65536 / 256, 256, 0, stream>>>(RT);
  cast_w<<<(D * D) / 2048, 256, 0, stream>>>(wq, W_QKV);
  cast_w<<<(D * D) / 2048, 256, 0, stream>>>(wk, W_QKV + (size_t)D * D);
  cast_w<<<(D * D) / 2048, 256, 0, stream>>>(wv, W_QKV + 2 * (size_t)D * D);
  cast_w<<<(D * D) / 2048, 256, 0, stream>>>(wo, W_O);
  cast_w<<<(FF * D) / 2048, 256, 0, stream>>>(wg, W_G);
  cast_w<<<(FF * D) / 2048, 256, 0, stream>>>(wu, W_U);
  cast_w<<<(FF * D) / 2048, 256, 0, stream>>>(wd, W_D);
  rmsnorm_cast<<<S, 256, 0, stream>>>(x, w_in, HB);
  gemm8<0><<<dim3(64, 1, 3), 512, 0, stream>>>(HB, W_QKV, QKVB, nullptr, S, D, D, D, D, 0,
                                               (long long)D * D, (long long)S * D);
  rope_apply<<<(S * 32 * 32) / 256, 256, 0, stream>>>(QKVB, QKVB + (size_t)S * D, RT);
  transpose_v<<<dim3(S / 64, 32), 256, 0, stream>>>(QKVB + 2 * (size_t)S * D, VT);
  flash_attn<<<dim3(S / 128, 32), 256, 0, stream>>>(QKVB, QKVB + (size_t)S * D, VT, ATTNB);
  if (splitO) {
    gemm8<3><<<dim3(64, 1, 4), 512, 0, stream>>>(ATTNB, W_O, OP, nullptr, S, D, 512, D, D, 512, 0, 0);
    reduce4<<<(S * D) / 1024, 256, 0, stream>>>(OP, x, X1, (size_t)S * D);
  } else {
    gemm8<1><<<dim3(64, 1, 1), 512, 0, stream>>>(ATTNB, W_O, X1, x, S, D, D, D, D, 0, 0, 0);
  }
  rmsnorm_cast<<<S, 256, 0, stream>>>(X1, w_pn, H2B);
  gemm8<0><<<dim3(256, 1, 1), 512, 0, stream>>>(H2B, W_G, GATEB, nullptr, S, FF, D, D, D, 0, 0, 0);
  gemm8<2><<<dim3(256, 1, 1), 512, 0, stream>>>(H2B, W_U, PRODB, GATEB, S, FF, D, D, D, 0, 0, 0);
  gemm8<3><<<dim3(64, 1, 4), 512, 0, stream>>>(PRODB, W_D, DP, nullptr, S, D, 2048, FF, FF, 2048, 0, 0);
  reduce4<<<(S * D) / 1024, 256, 0, stream>>>(DP, X1, out, (size_t)S * D);
  (void)in_sizes; (void)n_in; (void)out_size;
}

// Round 8
// 543.395 us; speedup vs baseline: 1.3274x; 1.0311x over previous
//
#include <hip/hip_runtime.h>

typedef unsigned short u16;
typedef unsigned int u32;
typedef __attribute__((ext_vector_type(2))) unsigned int u32x2;
typedef __attribute__((ext_vector_type(8))) unsigned short u16x8;
typedef __attribute__((ext_vector_type(8))) __bf16 bf16x8;
typedef __attribute__((ext_vector_type(4))) float f32x4;

#define DEV __device__ __forceinline__

DEV u16 f2bf(float f) {
  unsigned u = __builtin_bit_cast(unsigned, f);
  u += 0x7FFFu + ((u >> 16) & 1u);
  return (u16)(u >> 16);
}
DEV float bf2f(u16 h) {
  unsigned u = ((unsigned)h) << 16;
  return __builtin_bit_cast(float, u);
}
DEV u32 cvtpk(float lo, float hi) {
  u32 r;
  asm("v_cvt_pk_bf16_f32 %0, %1, %2" : "=v"(r) : "v"(lo), "v"(hi));
  return r;
}
DEV f32x4 mfma16(u16x8 a, u16x8 b, f32x4 c) {
  return __builtin_amdgcn_mfma_f32_16x16x32_bf16(
      __builtin_bit_cast(bf16x8, a), __builtin_bit_cast(bf16x8, b), c, 0, 0, 0);
}
DEV void gload_lds16(const void* g, void* l) {
  __builtin_amdgcn_global_load_lds(
      (const __attribute__((address_space(1))) void*)g,
      (__attribute__((address_space(3))) void*)l, 16, 0, 0);
}

// ---------------- weight cast fp32 -> bf16 ----------------
__global__ __launch_bounds__(256) void cast_w(const float* __restrict__ in, u16* __restrict__ out) {
  size_t i = ((size_t)blockIdx.x * 256 + threadIdx.x) * 8;
  float4 a = *(const float4*)(in + i);
  float4 b = *(const float4*)(in + i + 4);
  u16x8 o;
  o[0] = f2bf(a.x); o[1] = f2bf(a.y); o[2] = f2bf(a.z); o[3] = f2bf(a.w);
  o[4] = f2bf(b.x); o[5] = f2bf(b.y); o[6] = f2bf(b.z); o[7] = f2bf(b.w);
  *(u16x8*)(out + i) = o;
}

// ---------------- RMSNorm (fp32 in) -> bf16 out ----------------
__global__ __launch_bounds__(256) void rmsnorm_cast(const float* __restrict__ x, const float* __restrict__ w,
                                                    u16* __restrict__ out) {
  const int row = blockIdx.x, tid = threadIdx.x;
  const float* xr = x + (size_t)row * 2048;
  float4 a = *(const float4*)(xr + tid * 8);
  float4 b = *(const float4*)(xr + tid * 8 + 4);
  float ss = a.x * a.x + a.y * a.y + a.z * a.z + a.w * a.w +
             b.x * b.x + b.y * b.y + b.z * b.z + b.w * b.w;
#pragma unroll
  for (int off = 32; off; off >>= 1) ss += __shfl_xor(ss, off);
  __shared__ float part[4];
  if ((tid & 63) == 0) part[tid >> 6] = ss;
  __syncthreads();
  float tot = part[0] + part[1] + part[2] + part[3];
  float r = rsqrtf(tot * (1.0f / 2048.0f) + 1e-5f);
  float4 wa = *(const float4*)(w + tid * 8);
  float4 wb = *(const float4*)(w + tid * 8 + 4);
  u16x8 o;
  o[0] = f2bf(a.x * r * wa.x); o[1] = f2bf(a.y * r * wa.y);
  o[2] = f2bf(a.z * r * wa.z); o[3] = f2bf(a.w * r * wa.w);
  o[4] = f2bf(b.x * r * wb.x); o[5] = f2bf(b.y * r * wb.y);
  o[6] = f2bf(b.z * r * wb.z); o[7] = f2bf(b.w * r * wb.w);
  *(u16x8*)(out + (size_t)row * 2048 + tid * 8) = o;
}

// ============ 256x256-tile, 8-wave, 8-phase NT GEMM (counted vmcnt) ============
template <int EPI>
__global__ __launch_bounds__(512) void gemm8(const u16* __restrict__ Ag, const u16* __restrict__ Bg,
                                             void* __restrict__ outp, const void* __restrict__ extra,
                                             int M, int N, int KC, int lda, int ldb, int koffStride,
                                             long long bStrideB, long long bStrideO) {
  __shared__ u16 lds[32768];  // 64 KiB
  const int z = blockIdx.z;
  const u16* Ap = Ag;
  const u16* Bp = Bg + (EPI == 0 ? (size_t)z * bStrideB : (size_t)0);
  const int koff = (EPI == 3) ? z * koffStride : 0;
  const int nbx = N >> 8;
  const int q8 = gridDim.x >> 3;  // grids are multiples of 8
  const int gid = blockIdx.x;
  const int lid = (gid & 7) * q8 + (gid >> 3);  // XCD-contiguous logical id (T1)
  const int by = lid / nbx, bx = lid % nbx;
  const int bm = by << 8, bn = bx << 8;
  const int tid = threadIdx.x;
  const int w = tid >> 6, l = tid & 63;
  const int wr = w >> 2, wc = w & 3;
  const int l16 = l & 15, l4 = l >> 4;
  const int NT2 = KC >> 6, NTT = KC >> 5;
  const int srow = (w << 4) + (l >> 2);
  const int scolb = ((l & 3) << 4) ^ (((l >> 3) & 1) << 5) ^ (((l >> 4) & 1) << 4);
  char* ldsb = (char*)lds;

  auto STG = [&](const u16* src, int ldx, int rowBase, int kt, int ldsOffU16) {
    const char* g = (const char*)src + ((size_t)(rowBase + srow) * ldx + kt) * 2 + scolb;
    gload_lds16(g, ldsb + ldsOffU16 * 2 + (w << 10));
  };

  f32x4 acc[8][4] = {};
  u16x8 a[4], b[4];

  auto LDA4 = [&](int bufU16, int mh) {
#pragma unroll
    for (int j = 0; j < 4; ++j) {
      int row = wr * 128 + mh * 64 + j * 16 + l16;
      int off = (row << 5) + (l4 << 3);
      off ^= (((row >> 1) & 1) << 4) | (((row >> 2) & 1) << 3);
      a[j] = *(const u16x8*)(lds + bufU16 + off);
    }
  };
  auto LDB2 = [&](int bufU16, int nh) {
#pragma unroll
    for (int j = 0; j < 2; ++j) {
      int row = wc * 64 + nh * 32 + j * 16 + l16;
      int off = (row << 5) + (l4 << 3);
      off ^= (((row >> 1) & 1) << 4) | (((row >> 2) & 1) << 3);
      b[nh * 2 + j] = *(const u16x8*)(lds + bufU16 + 8192 + off);
    }
  };
  auto MM = [&](int mh, int nh) {
    __builtin_amdgcn_s_setprio(1);
#pragma unroll
    for (int mt = 0; mt < 4; ++mt)
#pragma unroll
      for (int nt = 0; nt < 2; ++nt)
        acc[mh * 4 + mt][nh * 2 + nt] = mfma16(a[mt], b[nh * 2 + nt], acc[mh * 4 + mt][nh * 2 + nt]);
    __builtin_amdgcn_s_setprio(0);
  };

  STG(Ap, lda, bm, koff, 0);
  STG(Ap, lda, bm + 128, koff, 4096);
  STG(Bp, ldb, bn, koff, 8192);
  STG(Bp, ldb, bn + 128, koff, 12288);
  STG(Ap, lda, bm, koff + 32, 16384);
  STG(Ap, lda, bm + 128, koff + 32, 20480);
  asm volatile("s_waitcnt vmcnt(2)" ::: "memory");
  __builtin_amdgcn_sched_barrier(0);
  __builtin_amdgcn_s_barrier();

  for (int it = 0; it < NT2; ++it) {
    const int t1 = 2 * it + 1, t2 = 2 * it + 2, t3 = 2 * it + 3;
    const int k1 = koff + (t1 < NTT ? t1 * 32 : 0);
    const int k2 = koff + (t2 < NTT ? t2 * 32 : 0);
    const int k3 = koff + (t3 < NTT ? t3 * 32 : 0);
    LDA4(0, 0); LDB2(0, 0);
    STG(Bp, ldb, bn, k1, 24576);
    __builtin_amdgcn_s_barrier();
    MM(0, 0);
    __builtin_amdgcn_s_barrier();
    LDB2(0, 1);
    STG(Bp, ldb, bn + 128, k1, 28672);
    __builtin_amdgcn_s_barrier();
    MM(0, 1);
    __builtin_amdgcn_s_barrier();
    LDA4(0, 1);
    __builtin_amdgcn_s_barrier();
    MM(1, 0);
    __builtin_amdgcn_s_barrier();
    STG(Ap, lda, bm, k2, 0);
    STG(Ap, lda, bm + 128, k2, 4096);
    asm volatile("s_waitcnt vmcnt(2)" ::: "memory");
    __builtin_amdgcn_sched_barrier(0);
    __builtin_amdgcn_s_barrier();
    MM(1, 1);
    __builtin_amdgcn_s_barrier();
    LDA4(16384, 0); LDB2(16384, 0);
    STG(Bp, ldb, bn, k2, 8192);
    __builtin_amdgcn_s_barrier();
    MM(0, 0);
    __builtin_amdgcn_s_barrier();
    LDB2(16384, 1);
    STG(Bp, ldb, bn + 128, k2, 12288);
    __builtin_amdgcn_s_barrier();
    MM(0, 1);
    __builtin_amdgcn_s_barrier();
    LDA4(16384, 1);
    __builtin_amdgcn_s_barrier();
    MM(1, 0);
    __builtin_amdgcn_s_barrier();
    STG(Ap, lda, bm, k3, 16384);
    STG(Ap, lda, bm + 128, k3, 20480);
    asm volatile("s_waitcnt vmcnt(2)" ::: "memory");
    __builtin_amdgcn_sched_barrier(0);
    __builtin_amdgcn_s_barrier();
    MM(1, 1);
    __builtin_amdgcn_s_barrier();
  }

#pragma unroll
  for (int i = 0; i < 8; ++i)
#pragma unroll
    for (int j = 0; j < 4; ++j)
#pragma unroll
      for (int r = 0; r < 4; ++r) {
        const int row = bm + wr * 128 + i * 16 + l4 * 4 + r;
        const int col = bn + wc * 64 + j * 16 + l16;
        const size_t idx = (size_t)row * N + col;
        float v = acc[i][j][r];
        if (EPI == 0) {
          ((u16*)outp)[(size_t)z * bStrideO + idx] = f2bf(v);
        } else if (EPI == 1) {
          ((float*)outp)[idx] = v + ((const float*)extra)[idx];
        } else if (EPI == 2) {
          float g = bf2f(((const u16*)extra)[idx]);
          float sig = 1.0f / (1.0f + __expf(-v));
          ((u16*)outp)[idx] = f2bf(g * v * sig);
        } else {
          ((float*)outp)[(size_t)z * M * N + idx] = v;
        }
      }
}

// ---------------- split-K reduce: out = p0+p1+p2+p3 + res ----------------
__global__ __launch_bounds__(256) void reduce4(const float* __restrict__ p, const float* __restrict__ res,
                                               float* __restrict__ out, size_t n) {
  size_t i = ((size_t)blockIdx.x * 256 + threadIdx.x) * 4;
  float4 a = *(const float4*)(p + i);
  float4 b = *(const float4*)(p + n + i);
  float4 c = *(const float4*)(p + 2 * n + i);
  float4 d = *(const float4*)(p + 3 * n + i);
  float4 r = *(const float4*)(res + i);
  float4 o;
  o.x = a.x + b.x + c.x + d.x + r.x;
  o.y = a.y + b.y + c.y + d.y + r.y;
  o.z = a.z + b.z + c.z + d.z + r.z;
  o.w = a.w + b.w + c.w + d.w + r.w;
  *(float4*)(out + i) = o;
}

// ---------------- RoPE ----------------
__global__ __launch_bounds__(256) void rope_table(float2* __restrict__ tab) {
  int idx = blockIdx.x * 256 + threadIdx.x;  // S*32 = 65536
  int pos = idx >> 5, i = idx & 31;
  float inv = __expf(-(float)(2 * i) * (9.210340371976184f / 64.0f));
  float a = (float)pos * inv;
  float s, c;
  __sincosf(a, &s, &c);
  tab[idx] = make_float2(c, s);
}

__global__ __launch_bounds__(256) void rope_apply(u16* __restrict__ q, u16* __restrict__ k,
                                                  const float2* __restrict__ tab) {
  int idx = blockIdx.x * 256 + threadIdx.x;  // S*H*32 = 2M
  int i = idx & 31;
  int hh = (idx >> 5) & 31;
  int pos = idx >> 10;
  float2 cs = tab[(pos << 5) + i];
  size_t base = (size_t)pos * 2048 + hh * 64 + i;
  float a0 = bf2f(q[base]), a1 = bf2f(q[base + 32]);
  q[base] = f2bf(a0 * cs.x - a1 * cs.y);
  q[base + 32] = f2bf(a1 * cs.x + a0 * cs.y);
  float b0 = bf2f(k[base]), b1 = bf2f(k[base + 32]);
  k[base] = f2bf(b0 * cs.x - b1 * cs.y);
  k[base + 32] = f2bf(b1 * cs.x + b0 * cs.y);
}

// ---------------- V transpose: v[S][D] -> vT[h][d][S] ----------------
__global__ __launch_bounds__(256) void transpose_v(const u16* __restrict__ v, u16* __restrict__ vt) {
  __shared__ u16 t[64][72];
  const int t0 = blockIdx.x * 64, h = blockIdx.y, tid = threadIdx.x;
  {
    const int r = tid >> 3, c8 = (tid & 7) * 8;
#pragma unroll
    for (int j = 0; j < 2; ++j) {
      u16x8 val = *(const u16x8*)(v + (size_t)(t0 + r + 32 * j) * 2048 + h * 64 + c8);
      *(u16x8*)&t[r + 32 * j][c8] = val;
    }
  }
  __syncthreads();
  const int d = tid >> 2, q = (tid & 3) * 16;
  u16x8 lo, hi;
#pragma unroll
  for (int e = 0; e < 8; ++e) lo[e] = t[q + e][d];
#pragma unroll
  for (int e = 0; e < 8; ++e) hi[e] = t[q + 8 + e][d];
  *(u16x8*)(vt + (size_t)(h * 64 + d) * 2048 + t0 + q) = lo;
  *(u16x8*)(vt + (size_t)(h * 64 + d) * 2048 + t0 + q + 8) = hi;
}

// ---------------- Flash attention v6: swapped QK^T + packed in-register P ----------------
// v5 structure (block-shared swizzled LDS K/V staging, head-grouped XCD remap,
// Q pre-scale, defer-max, deferred sum) with T12-style S^T orientation:
// sacc = mfma(K, Q) -> each lane holds a full q-row (l16) slice, kv in reg pairs.
// P: 16x v_cvt_pk_bf16_f32 + 8x ds_write_b64 (vs 32x f2bf + 32x ds_write_b16).
// Row reduces are 2-stage (xor 16/32), only on rescale path + once at end.
__global__ __launch_bounds__(256) void flash_attn(const u16* __restrict__ qb, const u16* __restrict__ kb,
                                                  const u16* __restrict__ vt, u16* __restrict__ ob) {
  const int id = blockIdx.x + (blockIdx.y << 4);
  const int h = ((id & 7) << 2) | ((id >> 3) & 3);  // 4 heads per XCD -> K/V L2-resident
  const int q0 = (id >> 5) << 7;
  const int w = threadIdx.x >> 6, l = threadIdx.x & 63;
  const int l16 = l & 15, l4 = l >> 4;
  const float C = 0.125f * 1.4426950408889634f;  // folded into Q
  const float THR = 11.541560327111708f;         // 8 nats in exp2 domain
  __shared__ u16 KV[2][2][64 * 64];  // [buf][K|V][row][64], XOR-swizzled chunks
  __shared__ u32 P32[4][32 * 36];    // per-wave packed P, rows stride 36 u32
  const int srow8 = l >> 3;
  const int schunk = (l & 7) ^ srow8;

  auto STAGE = [&](int t0, int buf) {
#pragma unroll
    for (int j = 0; j < 2; ++j) {
      const int rg = w * 16 + j * 8;
      const int row = rg + srow8;
      gload_lds16(kb + (size_t)(t0 + row) * 2048 + h * 64 + schunk * 8, &KV[buf][0][rg * 64]);
      gload_lds16(vt + (size_t)(h * 64 + row) * 2048 + t0 + schunk * 8, &KV[buf][1][rg * 64]);
    }
  };

  u16x8 qf[2][2];
#pragma unroll
  for (int rt = 0; rt < 2; ++rt)
#pragma unroll
    for (int kh = 0; kh < 2; ++kh) {
      u16x8 q = *(const u16x8*)(qb + (size_t)(q0 + w * 32 + rt * 16 + l16) * 2048 + h * 64 + kh * 32 + l4 * 8);
#pragma unroll
      for (int e = 0; e < 8; ++e) q[e] = f2bf(bf2f(q[e]) * C);
      qf[rt][kh] = q;
    }
  float mrun[2], lrun[2];
  f32x4 oacc[2][4] = {};
#pragma unroll
  for (int i = 0; i < 2; ++i) { mrun[i] = -1e30f; lrun[i] = 0.f; }

  auto TILE = [&](int t0, int buf) {
    // S^T = K . Q^T : sacc[rt][tt] regs r -> S[q = rt*16+l16][kv = tt*16+l4*4+r]
    f32x4 sacc[2][4] = {};
#pragma unroll
    for (int kh = 0; kh < 2; ++kh)
#pragma unroll
      for (int tt = 0; tt < 4; ++tt) {
        const int row = tt * 16 + l16;
        const int ch = (kh * 4 + l4) ^ (row & 7);
        u16x8 kf = *(const u16x8*)&KV[buf][0][row * 64 + ch * 8];
#pragma unroll
        for (int rt = 0; rt < 2; ++rt)
          sacc[rt][tt] = mfma16(kf, qf[rt][kh], sacc[rt][tt]);  // swapped operands
      }
    // defer-max check (per lane: full q-row slice of 16 kv values per rt)
    float pmax[2];
    int ok = 1;
#pragma unroll
    for (int rt = 0; rt < 2; ++rt) {
      float m01 = fmaxf(fmaxf(sacc[rt][0][0], sacc[rt][0][1]), fmaxf(sacc[rt][0][2], sacc[rt][0][3]));
      float m1 = fmaxf(fmaxf(sacc[rt][1][0], sacc[rt][1][1]), fmaxf(sacc[rt][1][2], sacc[rt][1][3]));
      float m2 = fmaxf(fmaxf(sacc[rt][2][0], sacc[rt][2][1]), fmaxf(sacc[rt][2][2], sacc[rt][2][3]));
      float m3 = fmaxf(fmaxf(sacc[rt][3][0], sacc[rt][3][1]), fmaxf(sacc[rt][3][2], sacc[rt][3][3]));
      pmax[rt] = fmaxf(fmaxf(m01, m1), fmaxf(m2, m3));
      ok &= (pmax[rt] <= mrun[rt] + THR) ? 1 : 0;
    }
    if (!__all(ok)) {
      float sfac[2];
#pragma unroll
      for (int rt = 0; rt < 2; ++rt) {
        float mx = pmax[rt];
        mx = fmaxf(mx, __shfl_xor(mx, 16));
        mx = fmaxf(mx, __shfl_xor(mx, 32));
        float mnew = fmaxf(mrun[rt], mx);
        sfac[rt] = exp2f(mrun[rt] - mnew);
        mrun[rt] = mnew;
        lrun[rt] *= sfac[rt];
      }
      // redistribute sfac (held at lane l16 = q-row) to oacc rows (q-row = l4*4+r)
#pragma unroll
      for (int rt = 0; rt < 2; ++rt) {
        float sfo[4];
#pragma unroll
        for (int r = 0; r < 4; ++r) sfo[r] = __shfl(sfac[rt], (l & 48) + l4 * 4 + r);
#pragma unroll
        for (int nt = 0; nt < 4; ++nt)
#pragma unroll
          for (int r = 0; r < 4; ++r) oacc[rt][nt][r] *= sfo[r];
      }
    }
    // P = exp2(S - mrun); pack pairs; write b64; per-lane partial row-sum
#pragma unroll
    for (int rt = 0; rt < 2; ++rt) {
      const int rowOff = (rt * 16 + l16) * 36 + l4 * 2;
#pragma unroll
      for (int tt = 0; tt < 4; ++tt) {
        float p0 = exp2f(sacc[rt][tt][0] - mrun[rt]);
        float p1 = exp2f(sacc[rt][tt][1] - mrun[rt]);
        float p2 = exp2f(sacc[rt][tt][2] - mrun[rt]);
        float p3 = exp2f(sacc[rt][tt][3] - mrun[rt]);
        lrun[rt] += (p0 + p1) + (p2 + p3);
        u32x2 pk;
        pk.x = cvtpk(p0, p1);
        pk.y = cvtpk(p2, p3);
        *(u32x2*)&P32[w][rowOff + tt * 8] = pk;
      }
    }
    // PV: A = P rows (q), B = V^T rows (d)
#pragma unroll
    for (int ks = 0; ks < 2; ++ks) {
      u16x8 pf[2];
#pragma unroll
      for (int rt = 0; rt < 2; ++rt)
        pf[rt] = *(const u16x8*)&P32[w][(rt * 16 + l16) * 36 + ks * 16 + l4 * 4];
#pragma unroll
      for (int nt = 0; nt < 4; ++nt) {
        const int row = nt * 16 + l16;
        const int ch = (ks * 4 + l4) ^ (row & 7);
        u16x8 vf = *(const u16x8*)&KV[buf][1][row * 64 + ch * 8];
#pragma unroll
        for (int rt = 0; rt < 2; ++rt)
          oacc[rt][nt] = mfma16(pf[rt], vf, oacc[rt][nt]);
      }
    }
  };

  STAGE(0, 0);
  __syncthreads();
  int buf = 0;
  for (int t = 0; t < 32; ++t) {
    if (t < 31) STAGE((t + 1) * 64, buf ^ 1);
    TILE(t * 64, buf);
    __syncthreads();
    buf ^= 1;
  }
  // final 2-stage sum reduce (lanes sharing a q-row differ in bits 4-5)
#pragma unroll
  for (int rt = 0; rt < 2; ++rt) {
    lrun[rt] += __shfl_xor(lrun[rt], 16);
    lrun[rt] += __shfl_xor(lrun[rt], 32);
  }
#pragma unroll
  for (int rt = 0; rt < 2; ++rt) {
    float linv[4];
#pragma unroll
    for (int r = 0; r < 4; ++r) linv[r] = 1.0f / __shfl(lrun[rt], (l & 48) + l4 * 4 + r);
#pragma unroll
    for (int r = 0; r < 4; ++r)
#pragma unroll
      for (int nt = 0; nt < 4; ++nt)
        ob[(size_t)(q0 + w * 32 + rt * 16 + l4 * 4 + r) * 2048 + h * 64 + nt * 16 + l16] =
            f2bf(oacc[rt][nt][r] * linv[r]);
  }
}

extern "C" void kernel_launch(void* const* d_in, const int* in_sizes, int n_in,
                              void* d_out, int out_size, void* d_ws, size_t ws_size,
                              hipStream_t stream) {
  const float* x    = (const float*)d_in[0];
  const float* w_in = (const float*)d_in[1];
  const float* wq   = (const float*)d_in[2];
  const float* wk   = (const float*)d_in[3];
  const float* wv   = (const float*)d_in[4];
  const float* wo   = (const float*)d_in[5];
  const float* w_pn = (const float*)d_in[6];
  const float* wg   = (const float*)d_in[7];
  const float* wu   = (const float*)d_in[8];
  const float* wd   = (const float*)d_in[9];
  float* out = (float*)d_out;
  char* ws = (char*)d_ws;
  const size_t MB = 1ull << 20;
  const int S = 2048, D = 2048, FF = 8192;

  u16* W_QKV = (u16*)(ws);               // 24 MB
  u16* W_O   = (u16*)(ws + 24 * MB);     // 8 MB
  u16* W_G   = (u16*)(ws + 32 * MB);     // 32 MB
  u16* W_U   = (u16*)(ws + 64 * MB);     // 32 MB
  u16* W_D   = (u16*)(ws + 96 * MB);     // 32 MB
  u16* HB    = (u16*)(ws + 128 * MB);    // 8 MB
  u16* QKVB  = (u16*)(ws + 136 * MB);    // 24 MB (q,k,v)
  u16* VT    = (u16*)(ws + 160 * MB);    // 8 MB
  u16* ATTNB = (u16*)(ws + 168 * MB);    // 8 MB
  float* X1  = (float*)(ws + 176 * MB);  // 16 MB
  u16* H2B   = (u16*)(ws + 192 * MB);    // 8 MB
  float2* RT = (float2*)(ws + 200 * MB); // 0.5 MB
  u16* GATEB = (u16*)(ws);               // 32 MB, overlays W_QKV+W_O (dead after O-proj)
  u16* PRODB = (u16*)(ws + 136 * MB);    // 32 MB, overlays QKVB+VT (dead after attention)
  float* DP  = (float*)(ws);             // 64 MB down-proj partials
  float* OP  = (float*)(ws + 208 * MB);  // 64 MB O-proj partials (only if ws permits)
  const bool splitO = ws_size >= 272 * MB;

  rope_table<<<65536 / 256, 256, 0, stream>>>(RT);
  cast_w<<<(D * D) / 2048, 256, 0, stream>>>(wq, W_QKV);
  cast_w<<<(D * D) / 2048, 256, 0, stream>>>(wk, W_QKV + (size_t)D * D);
  cast_w<<<(D * D) / 2048, 256, 0, stream>>>(wv, W_QKV + 2 * (size_t)D * D);
  cast_w<<<(D * D) / 2048, 256, 0, stream>>>(wo, W_O);
  cast_w<<<(FF * D) / 2048, 256, 0, stream>>>(wg, W_G);
  cast_w<<<(FF * D) / 2048, 256, 0, stream>>>(wu, W_U);
  cast_w<<<(FF * D) / 2048, 256, 0, stream>>>(wd, W_D);
  rmsnorm_cast<<<S, 256, 0, stream>>>(x, w_in, HB);
  gemm8<0><<<dim3(64, 1, 3), 512, 0, stream>>>(HB, W_QKV, QKVB, nullptr, S, D, D, D, D, 0,
                                               (long long)D * D, (long long)S * D);
  rope_apply<<<(S * 32 * 32) / 256, 256, 0, stream>>>(QKVB, QKVB + (size_t)S * D, RT);
  transpose_v<<<dim3(S / 64, 32), 256, 0, stream>>>(QKVB + 2 * (size_t)S * D, VT);
  flash_attn<<<dim3(S / 128, 32), 256, 0, stream>>>(QKVB, QKVB + (size_t)S * D, VT, ATTNB);
  if (splitO) {
    gemm8<3><<<dim3(64, 1, 4), 512, 0, stream>>>(ATTNB, W_O, OP, nullptr, S, D, 512, D, D, 512, 0, 0);
    reduce4<<<(S * D) / 1024, 256, 0, stream>>>(OP, x, X1, (size_t)S * D);
  } else {
    gemm8<1><<<dim3(64, 1, 1), 512, 0, stream>>>(ATTNB, W_O, X1, x, S, D, D, D, D, 0, 0, 0);
  }
  rmsnorm_cast<<<S, 256, 0, stream>>>(X1, w_pn, H2B);
  gemm8<0><<<dim3(256, 1, 1), 512, 0, stream>>>(H2B, W_G, GATEB, nullptr, S, FF, D, D, D, 0, 0, 0);
  gemm8<2><<<dim3(256, 1, 1), 512, 0, stream>>>(H2B, W_U, PRODB, GATEB, S, FF, D, D, D, 0, 0, 0);
  gemm8<3><<<dim3(64, 1, 4), 512, 0, stream>>>(PRODB, W_D, DP, nullptr, S, D, 2048, FF, FF, 2048, 0, 0);
  reduce4<<<(S * D) / 1024, 256, 0, stream>>>(DP, X1, out, (size_t)S * D);
  (void)in_sizes; (void)n_in; (void)out_size;
}

// Round 9
// 495.888 us; speedup vs baseline: 1.4546x; 1.0958x over previous
//
#include <hip/hip_runtime.h>

typedef unsigned short u16;
typedef unsigned int u32;
typedef __attribute__((ext_vector_type(2))) unsigned int u32x2;
typedef __attribute__((ext_vector_type(8))) unsigned short u16x8;
typedef __attribute__((ext_vector_type(8))) __bf16 bf16x8;
typedef __attribute__((ext_vector_type(4))) float f32x4;

#define DEV __device__ __forceinline__

DEV u16 f2bf(float f) {
  unsigned u = __builtin_bit_cast(unsigned, f);
  u += 0x7FFFu + ((u >> 16) & 1u);
  return (u16)(u >> 16);
}
DEV float bf2f(u16 h) {
  unsigned u = ((unsigned)h) << 16;
  return __builtin_bit_cast(float, u);
}
DEV u32 cvtpk(float lo, float hi) {
  u32 r;
  asm("v_cvt_pk_bf16_f32 %0, %1, %2" : "=v"(r) : "v"(lo), "v"(hi));
  return r;
}
DEV f32x4 mfma16(u16x8 a, u16x8 b, f32x4 c) {
  return __builtin_amdgcn_mfma_f32_16x16x32_bf16(
      __builtin_bit_cast(bf16x8, a), __builtin_bit_cast(bf16x8, b), c, 0, 0, 0);
}
DEV void gload_lds16(const void* g, void* l) {
  __builtin_amdgcn_global_load_lds(
      (const __attribute__((address_space(1))) void*)g,
      (__attribute__((address_space(3))) void*)l, 16, 0, 0);
}

// ---------------- weight cast fp32 -> bf16 ----------------
__global__ __launch_bounds__(256) void cast_w(const float* __restrict__ in, u16* __restrict__ out) {
  size_t i = ((size_t)blockIdx.x * 256 + threadIdx.x) * 8;
  float4 a = *(const float4*)(in + i);
  float4 b = *(const float4*)(in + i + 4);
  u16x8 o;
  o[0] = f2bf(a.x); o[1] = f2bf(a.y); o[2] = f2bf(a.z); o[3] = f2bf(a.w);
  o[4] = f2bf(b.x); o[5] = f2bf(b.y); o[6] = f2bf(b.z); o[7] = f2bf(b.w);
  *(u16x8*)(out + i) = o;
}

// ---------------- RMSNorm (fp32 in) -> bf16 out ----------------
__global__ __launch_bounds__(256) void rmsnorm_cast(const float* __restrict__ x, const float* __restrict__ w,
                                                    u16* __restrict__ out) {
  const int row = blockIdx.x, tid = threadIdx.x;
  const float* xr = x + (size_t)row * 2048;
  float4 a = *(const float4*)(xr + tid * 8);
  float4 b = *(const float4*)(xr + tid * 8 + 4);
  float ss = a.x * a.x + a.y * a.y + a.z * a.z + a.w * a.w +
             b.x * b.x + b.y * b.y + b.z * b.z + b.w * b.w;
#pragma unroll
  for (int off = 32; off; off >>= 1) ss += __shfl_xor(ss, off);
  __shared__ float part[4];
  if ((tid & 63) == 0) part[tid >> 6] = ss;
  __syncthreads();
  float tot = part[0] + part[1] + part[2] + part[3];
  float r = rsqrtf(tot * (1.0f / 2048.0f) + 1e-5f);
  float4 wa = *(const float4*)(w + tid * 8);
  float4 wb = *(const float4*)(w + tid * 8 + 4);
  u16x8 o;
  o[0] = f2bf(a.x * r * wa.x); o[1] = f2bf(a.y * r * wa.y);
  o[2] = f2bf(a.z * r * wa.z); o[3] = f2bf(a.w * r * wa.w);
  o[4] = f2bf(b.x * r * wb.x); o[5] = f2bf(b.y * r * wb.y);
  o[6] = f2bf(b.z * r * wb.z); o[7] = f2bf(b.w * r * wb.w);
  *(u16x8*)(out + (size_t)row * 2048 + tid * 8) = o;
}

// ============ 256x256-tile, 8-wave, 8-phase NT GEMM, BK=64 (m201 geometry) ============
// C[m,n] = dot(A[m,:], B[n,:]).  2 K-tiles (BK=64) per iteration, double-buffered.
// LDS 128 KiB. 16 MFMA per phase; vmcnt(4) only at phases 4/8 (counted, never 0).
// Chunk-XOR swizzle: physical 16B-chunk = logical ^ (row&7), both staging & reads.
// EPI 0: bf16 out (+batch z). 1: fp32 = acc+extra(fp32). 2: bf16 = extra*silu(acc). 3: fp32 partial at z.
template <int EPI>
__global__ __launch_bounds__(512) void gemm8(const u16* __restrict__ Ag, const u16* __restrict__ Bg,
                                             void* __restrict__ outp, const void* __restrict__ extra,
                                             int M, int N, int KC, int lda, int ldb, int koffStride,
                                             long long bStrideB, long long bStrideO) {
  __shared__ u16 lds[65536];  // 128 KiB: A0 @0, B0 @16384, A1 @32768, B1 @49152 (u16)
  const int z = blockIdx.z;
  const u16* Ap = Ag;
  const u16* Bp = Bg + (EPI == 0 ? (size_t)z * bStrideB : (size_t)0);
  const int koff = (EPI == 3) ? z * koffStride : 0;
  const int nbx = N >> 8;
  const int cpx = nbx >> 3;  // N-tiles per XCD band (nbx is 8 or 32)
  const int gid = blockIdx.x;
  const int bx = (gid & 7) * cpx + ((gid >> 3) % cpx);
  const int by = (gid >> 3) / cpx;
  const int bm = by << 8, bn = bx << 8;
  const int tid = threadIdx.x;
  const int w = tid >> 6, l = tid & 63;
  const int wr = w >> 2, wc = w & 3;
  const int l16 = l & 15, l4 = l >> 4;
  const int NTT = KC >> 6, NT2 = KC >> 7;  // tiles of 64; iterations (2 tiles each)
  // staging constants: thread t covers chunk (i*512 + w*64 + l) of a 128x64 half-tile
  const int srow = l >> 3;                              // row offset within 8-row group
  const int scolB = (((l & 7) ^ srow) << 4);            // pre-swizzled source byte offset

  auto STG = [&](int halfU16, const u16* src, int ldx, int rowBase, int kt) {
#pragma unroll
    for (int i = 0; i < 2; ++i) {
      const int r = i * 64 + w * 8 + srow;
      const char* g = (const char*)(src + (size_t)(rowBase + r) * ldx + kt) + scolB;
      gload_lds16(g, (char*)lds + halfU16 * 2 + (i * 512 + w * 64) * 16);
    }
  };

  f32x4 acc[8][4] = {};
  u16x8 a[4][2], b[4][2];

  auto LDA8 = [&](int bufU16, int mh) {
#pragma unroll
    for (int j = 0; j < 4; ++j) {
      const int row = wr * 128 + mh * 64 + j * 16 + l16;
#pragma unroll
      for (int kk = 0; kk < 2; ++kk)
        a[j][kk] = *(const u16x8*)&lds[bufU16 + row * 64 + (((kk * 4 + l4) ^ (row & 7)) << 3)];
    }
  };
  auto LDB4 = [&](int bufU16, int nh) {
#pragma unroll
    for (int j = 0; j < 2; ++j) {
      const int nf = nh * 2 + j;
      const int row = wc * 64 + nf * 16 + l16;
#pragma unroll
      for (int kk = 0; kk < 2; ++kk)
        b[nf][kk] = *(const u16x8*)&lds[bufU16 + row * 64 + (((kk * 4 + l4) ^ (row & 7)) << 3)];
    }
  };
  auto MM = [&](int mh, int nh) {
    __builtin_amdgcn_s_setprio(1);
#pragma unroll
    for (int kk = 0; kk < 2; ++kk)
#pragma unroll
      for (int mt = 0; mt < 4; ++mt)
#pragma unroll
        for (int j = 0; j < 2; ++j)
          acc[mh * 4 + mt][nh * 2 + j] = mfma16(a[mt][kk], b[nh * 2 + j][kk], acc[mh * 4 + mt][nh * 2 + j]);
    __builtin_amdgcn_s_setprio(0);
  };

  // Prologue: tile0 A+B -> buf0 (8 loads), tile1 A -> buf1 (4 loads)
  STG(0, Ap, lda, bm, koff);
  STG(8192, Ap, lda, bm + 128, koff);
  STG(16384, Bp, ldb, bn, koff);
  STG(24576, Bp, ldb, bn + 128, koff);
  STG(32768, Ap, lda, bm, koff + 64);
  STG(40960, Ap, lda, bm + 128, koff + 64);
  asm volatile("s_waitcnt vmcnt(4)" ::: "memory");
  __builtin_amdgcn_sched_barrier(0);
  __builtin_amdgcn_s_barrier();

  for (int it = 0; it < NT2; ++it) {
    const int t1 = 2 * it + 1, t2 = 2 * it + 2, t3 = 2 * it + 3;
    const int k1 = koff + t1 * 64;                       // always < KC
    const int k2 = koff + (t2 < NTT ? t2 * 64 : 0);
    const int k3 = koff + (t3 < NTT ? t3 * 64 : 0);
    // ph1: read buf0 A(mh0)+B(nh0); stage t1.B half0 -> buf1
    LDA8(0, 0); LDB4(16384, 0);
    STG(49152, Bp, ldb, bn, k1);
    __builtin_amdgcn_s_barrier();
    MM(0, 0);
    __builtin_amdgcn_s_barrier();
    // ph2: read buf0 B(nh1); stage t1.B half1
    LDB4(16384, 1);
    STG(57344, Bp, ldb, bn + 128, k1);
    __builtin_amdgcn_s_barrier();
    MM(0, 1);
    __builtin_amdgcn_s_barrier();
    // ph3: read buf0 A(mh1)
    LDA8(0, 1);
    __builtin_amdgcn_s_barrier();
    MM(1, 0);
    __builtin_amdgcn_s_barrier();
    // ph4: stage t2.A -> buf0; counted vmcnt drains buf1 inputs
    STG(0, Ap, lda, bm, k2);
    STG(8192, Ap, lda, bm + 128, k2);
    asm volatile("s_waitcnt vmcnt(4)" ::: "memory");
    __builtin_amdgcn_sched_barrier(0);
    __builtin_amdgcn_s_barrier();
    MM(1, 1);
    __builtin_amdgcn_s_barrier();
    // ph5: read buf1 A(mh0)+B(nh0); stage t2.B half0 -> buf0
    LDA8(32768, 0); LDB4(49152, 0);
    STG(16384, Bp, ldb, bn, k2);
    __builtin_amdgcn_s_barrier();
    MM(0, 0);
    __builtin_amdgcn_s_barrier();
    // ph6: read buf1 B(nh1); stage t2.B half1
    LDB4(49152, 1);
    STG(24576, Bp, ldb, bn + 128, k2);
    __builtin_amdgcn_s_barrier();
    MM(0, 1);
    __builtin_amdgcn_s_barrier();
    // ph7: read buf1 A(mh1)
    LDA8(32768, 1);
    __builtin_amdgcn_s_barrier();
    MM(1, 0);
    __builtin_amdgcn_s_barrier();
    // ph8: stage t3.A -> buf1; counted vmcnt drains buf0 inputs
    STG(32768, Ap, lda, bm, k3);
    STG(40960, Ap, lda, bm + 128, k3);
    asm volatile("s_waitcnt vmcnt(4)" ::: "memory");
    __builtin_amdgcn_sched_barrier(0);
    __builtin_amdgcn_s_barrier();
    MM(1, 1);
    __builtin_amdgcn_s_barrier();
  }

#pragma unroll
  for (int i = 0; i < 8; ++i)
#pragma unroll
    for (int j = 0; j < 4; ++j)
#pragma unroll
      for (int r = 0; r < 4; ++r) {
        const int row = bm + wr * 128 + i * 16 + l4 * 4 + r;
        const int col = bn + wc * 64 + j * 16 + l16;
        const size_t idx = (size_t)row * N + col;
        float v = acc[i][j][r];
        if (EPI == 0) {
          ((u16*)outp)[(size_t)z * bStrideO + idx] = f2bf(v);
        } else if (EPI == 1) {
          ((float*)outp)[idx] = v + ((const float*)extra)[idx];
        } else if (EPI == 2) {
          float g = bf2f(((const u16*)extra)[idx]);
          float sig = 1.0f / (1.0f + __expf(-v));
          ((u16*)outp)[idx] = f2bf(g * v * sig);
        } else {
          ((float*)outp)[(size_t)z * M * N + idx] = v;
        }
      }
}

// ---------------- split-K reduce: out = p0+p1+p2+p3 + res ----------------
__global__ __launch_bounds__(256) void reduce4(const float* __restrict__ p, const float* __restrict__ res,
                                               float* __restrict__ out, size_t n) {
  size_t i = ((size_t)blockIdx.x * 256 + threadIdx.x) * 4;
  float4 a = *(const float4*)(p + i);
  float4 b = *(const float4*)(p + n + i);
  float4 c = *(const float4*)(p + 2 * n + i);
  float4 d = *(const float4*)(p + 3 * n + i);
  float4 r = *(const float4*)(res + i);
  float4 o;
  o.x = a.x + b.x + c.x + d.x + r.x;
  o.y = a.y + b.y + c.y + d.y + r.y;
  o.z = a.z + b.z + c.z + d.z + r.z;
  o.w = a.w + b.w + c.w + d.w + r.w;
  *(float4*)(out + i) = o;
}

// ---------------- RoPE ----------------
__global__ __launch_bounds__(256) void rope_table(float2* __restrict__ tab) {
  int idx = blockIdx.x * 256 + threadIdx.x;  // S*32 = 65536
  int pos = idx >> 5, i = idx & 31;
  float inv = __expf(-(float)(2 * i) * (9.210340371976184f / 64.0f));
  float a = (float)pos * inv;
  float s, c;
  __sincosf(a, &s, &c);
  tab[idx] = make_float2(c, s);
}

__global__ __launch_bounds__(256) void rope_apply(u16* __restrict__ q, u16* __restrict__ k,
                                                  const float2* __restrict__ tab) {
  int idx = blockIdx.x * 256 + threadIdx.x;  // S*H*32 = 2M
  int i = idx & 31;
  int hh = (idx >> 5) & 31;
  int pos = idx >> 10;
  float2 cs = tab[(pos << 5) + i];
  size_t base = (size_t)pos * 2048 + hh * 64 + i;
  float a0 = bf2f(q[base]), a1 = bf2f(q[base + 32]);
  q[base] = f2bf(a0 * cs.x - a1 * cs.y);
  q[base + 32] = f2bf(a1 * cs.x + a0 * cs.y);
  float b0 = bf2f(k[base]), b1 = bf2f(k[base + 32]);
  k[base] = f2bf(b0 * cs.x - b1 * cs.y);
  k[base + 32] = f2bf(b1 * cs.x + b0 * cs.y);
}

// ---------------- V transpose: v[S][D] -> vT[h][d][S] ----------------
__global__ __launch_bounds__(256) void transpose_v(const u16* __restrict__ v, u16* __restrict__ vt) {
  __shared__ u16 t[64][72];
  const int t0 = blockIdx.x * 64, h = blockIdx.y, tid = threadIdx.x;
  {
    const int r = tid >> 3, c8 = (tid & 7) * 8;
#pragma unroll
    for (int j = 0; j < 2; ++j) {
      u16x8 val = *(const u16x8*)(v + (size_t)(t0 + r + 32 * j) * 2048 + h * 64 + c8);
      *(u16x8*)&t[r + 32 * j][c8] = val;
    }
  }
  __syncthreads();
  const int d = tid >> 2, q = (tid & 3) * 16;
  u16x8 lo, hi;
#pragma unroll
  for (int e = 0; e < 8; ++e) lo[e] = t[q + e][d];
#pragma unroll
  for (int e = 0; e < 8; ++e) hi[e] = t[q + 8 + e][d];
  *(u16x8*)(vt + (size_t)(h * 64 + d) * 2048 + t0 + q) = lo;
  *(u16x8*)(vt + (size_t)(h * 64 + d) * 2048 + t0 + q + 8) = hi;
}

// ---------------- Flash attention v6: swapped QK^T + packed in-register P ----------------
__global__ __launch_bounds__(256) void flash_attn(const u16* __restrict__ qb, const u16* __restrict__ kb,
                                                  const u16* __restrict__ vt, u16* __restrict__ ob) {
  const int id = blockIdx.x + (blockIdx.y << 4);
  const int h = ((id & 7) << 2) | ((id >> 3) & 3);  // 4 heads per XCD -> K/V L2-resident
  const int q0 = (id >> 5) << 7;
  const int w = threadIdx.x >> 6, l = threadIdx.x & 63;
  const int l16 = l & 15, l4 = l >> 4;
  const float C = 0.125f * 1.4426950408889634f;  // folded into Q
  const float THR = 11.541560327111708f;         // 8 nats in exp2 domain
  __shared__ u16 KV[2][2][64 * 64];  // [buf][K|V][row][64], XOR-swizzled chunks
  __shared__ u32 P32[4][32 * 36];    // per-wave packed P, rows stride 36 u32
  const int srow8 = l >> 3;
  const int schunk = (l & 7) ^ srow8;

  auto STAGE = [&](int t0, int buf) {
#pragma unroll
    for (int j = 0; j < 2; ++j) {
      const int rg = w * 16 + j * 8;
      const int row = rg + srow8;
      gload_lds16(kb + (size_t)(t0 + row) * 2048 + h * 64 + schunk * 8, &KV[buf][0][rg * 64]);
      gload_lds16(vt + (size_t)(h * 64 + row) * 2048 + t0 + schunk * 8, &KV[buf][1][rg * 64]);
    }
  };

  u16x8 qf[2][2];
#pragma unroll
  for (int rt = 0; rt < 2; ++rt)
#pragma unroll
    for (int kh = 0; kh < 2; ++kh) {
      u16x8 q = *(const u16x8*)(qb + (size_t)(q0 + w * 32 + rt * 16 + l16) * 2048 + h * 64 + kh * 32 + l4 * 8);
#pragma unroll
      for (int e = 0; e < 8; ++e) q[e] = f2bf(bf2f(q[e]) * C);
      qf[rt][kh] = q;
    }
  float mrun[2], lrun[2];
  f32x4 oacc[2][4] = {};
#pragma unroll
  for (int i = 0; i < 2; ++i) { mrun[i] = -1e30f; lrun[i] = 0.f; }

  auto TILE = [&](int t0, int buf) {
    f32x4 sacc[2][4] = {};
#pragma unroll
    for (int kh = 0; kh < 2; ++kh)
#pragma unroll
      for (int tt = 0; tt < 4; ++tt) {
        const int row = tt * 16 + l16;
        const int ch = (kh * 4 + l4) ^ (row & 7);
        u16x8 kf = *(const u16x8*)&KV[buf][0][row * 64 + ch * 8];
#pragma unroll
        for (int rt = 0; rt < 2; ++rt)
          sacc[rt][tt] = mfma16(kf, qf[rt][kh], sacc[rt][tt]);  // swapped operands
      }
    float pmax[2];
    int ok = 1;
#pragma unroll
    for (int rt = 0; rt < 2; ++rt) {
      float m01 = fmaxf(fmaxf(sacc[rt][0][0], sacc[rt][0][1]), fmaxf(sacc[rt][0][2], sacc[rt][0][3]));
      float m1 = fmaxf(fmaxf(sacc[rt][1][0], sacc[rt][1][1]), fmaxf(sacc[rt][1][2], sacc[rt][1][3]));
      float m2 = fmaxf(fmaxf(sacc[rt][2][0], sacc[rt][2][1]), fmaxf(sacc[rt][2][2], sacc[rt][2][3]));
      float m3 = fmaxf(fmaxf(sacc[rt][3][0], sacc[rt][3][1]), fmaxf(sacc[rt][3][2], sacc[rt][3][3]));
      pmax[rt] = fmaxf(fmaxf(m01, m1), fmaxf(m2, m3));
      ok &= (pmax[rt] <= mrun[rt] + THR) ? 1 : 0;
    }
    if (!__all(ok)) {
      float sfac[2];
#pragma unroll
      for (int rt = 0; rt < 2; ++rt) {
        float mx = pmax[rt];
        mx = fmaxf(mx, __shfl_xor(mx, 16));
        mx = fmaxf(mx, __shfl_xor(mx, 32));
        float mnew = fmaxf(mrun[rt], mx);
        sfac[rt] = exp2f(mrun[rt] - mnew);
        mrun[rt] = mnew;
        lrun[rt] *= sfac[rt];
      }
#pragma unroll
      for (int rt = 0; rt < 2; ++rt) {
        float sfo[4];
#pragma unroll
        for (int r = 0; r < 4; ++r) sfo[r] = __shfl(sfac[rt], (l & 48) + l4 * 4 + r);
#pragma unroll
        for (int nt = 0; nt < 4; ++nt)
#pragma unroll
          for (int r = 0; r < 4; ++r) oacc[rt][nt][r] *= sfo[r];
      }
    }
#pragma unroll
    for (int rt = 0; rt < 2; ++rt) {
      const int rowOff = (rt * 16 + l16) * 36 + l4 * 2;
#pragma unroll
      for (int tt = 0; tt < 4; ++tt) {
        float p0 = exp2f(sacc[rt][tt][0] - mrun[rt]);
        float p1 = exp2f(sacc[rt][tt][1] - mrun[rt]);
        float p2 = exp2f(sacc[rt][tt][2] - mrun[rt]);
        float p3 = exp2f(sacc[rt][tt][3] - mrun[rt]);
        lrun[rt] += (p0 + p1) + (p2 + p3);
        u32x2 pk;
        pk.x = cvtpk(p0, p1);
        pk.y = cvtpk(p2, p3);
        *(u32x2*)&P32[w][rowOff + tt * 8] = pk;
      }
    }
#pragma unroll
    for (int ks = 0; ks < 2; ++ks) {
      u16x8 pf[2];
#pragma unroll
      for (int rt = 0; rt < 2; ++rt)
        pf[rt] = *(const u16x8*)&P32[w][(rt * 16 + l16) * 36 + ks * 16 + l4 * 4];
#pragma unroll
      for (int nt = 0; nt < 4; ++nt) {
        const int row = nt * 16 + l16;
        const int ch = (ks * 4 + l4) ^ (row & 7);
        u16x8 vf = *(const u16x8*)&KV[buf][1][row * 64 + ch * 8];
#pragma unroll
        for (int rt = 0; rt < 2; ++rt)
          oacc[rt][nt] = mfma16(pf[rt], vf, oacc[rt][nt]);
      }
    }
  };

  STAGE(0, 0);
  __syncthreads();
  int buf = 0;
  for (int t = 0; t < 32; ++t) {
    if (t < 31) STAGE((t + 1) * 64, buf ^ 1);
    TILE(t * 64, buf);
    __syncthreads();
    buf ^= 1;
  }
#pragma unroll
  for (int rt = 0; rt < 2; ++rt) {
    lrun[rt] += __shfl_xor(lrun[rt], 16);
    lrun[rt] += __shfl_xor(lrun[rt], 32);
  }
#pragma unroll
  for (int rt = 0; rt < 2; ++rt) {
    float linv[4];
#pragma unroll
    for (int r = 0; r < 4; ++r) linv[r] = 1.0f / __shfl(lrun[rt], (l & 48) + l4 * 4 + r);
#pragma unroll
    for (int r = 0; r < 4; ++r)
#pragma unroll
      for (int nt = 0; nt < 4; ++nt)
        ob[(size_t)(q0 + w * 32 + rt * 16 + l4 * 4 + r) * 2048 + h * 64 + nt * 16 + l16] =
            f2bf(oacc[rt][nt][r] * linv[r]);
  }
}

extern "C" void kernel_launch(void* const* d_in, const int* in_sizes, int n_in,
                              void* d_out, int out_size, void* d_ws, size_t ws_size,
                              hipStream_t stream) {
  const float* x    = (const float*)d_in[0];
  const float* w_in = (const float*)d_in[1];
  const float* wq   = (const float*)d_in[2];
  const float* wk   = (const float*)d_in[3];
  const float* wv   = (const float*)d_in[4];
  const float* wo   = (const float*)d_in[5];
  const float* w_pn = (const float*)d_in[6];
  const float* wg   = (const float*)d_in[7];
  const float* wu   = (const float*)d_in[8];
  const float* wd   = (const float*)d_in[9];
  float* out = (float*)d_out;
  char* ws = (char*)d_ws;
  const size_t MB = 1ull << 20;
  const int S = 2048, D = 2048, FF = 8192;

  u16* W_QKV = (u16*)(ws);               // 24 MB
  u16* W_O   = (u16*)(ws + 24 * MB);     // 8 MB
  u16* W_G   = (u16*)(ws + 32 * MB);     // 32 MB
  u16* W_U   = (u16*)(ws + 64 * MB);     // 32 MB
  u16* W_D   = (u16*)(ws + 96 * MB);     // 32 MB
  u16* HB    = (u16*)(ws + 128 * MB);    // 8 MB
  u16* QKVB  = (u16*)(ws + 136 * MB);    // 24 MB (q,k,v)
  u16* VT    = (u16*)(ws + 160 * MB);    // 8 MB
  u16* ATTNB = (u16*)(ws + 168 * MB);    // 8 MB
  float* X1  = (float*)(ws + 176 * MB);  // 16 MB
  u16* H2B   = (u16*)(ws + 192 * MB);    // 8 MB
  float2* RT = (float2*)(ws + 200 * MB); // 0.5 MB
  u16* GATEB = (u16*)(ws);               // 32 MB, overlays W_QKV+W_O (dead after O-proj)
  u16* PRODB = (u16*)(ws + 136 * MB);    // 32 MB, overlays QKVB+VT (dead after attention)
  float* DP  = (float*)(ws);             // 64 MB down-proj partials
  float* OP  = (float*)(ws + 208 * MB);  // 64 MB O-proj partials (only if ws permits)
  const bool splitO = ws_size >= 272 * MB;

  rope_table<<<65536 / 256, 256, 0, stream>>>(RT);
  cast_w<<<(D * D) / 2048, 256, 0, stream>>>(wq, W_QKV);
  cast_w<<<(D * D) / 2048, 256, 0, stream>>>(wk, W_QKV + (size_t)D * D);
  cast_w<<<(D * D) / 2048, 256, 0, stream>>>(wv, W_QKV + 2 * (size_t)D * D);
  cast_w<<<(D * D) / 2048, 256, 0, stream>>>(wo, W_O);
  cast_w<<<(FF * D) / 2048, 256, 0, stream>>>(wg, W_G);
  cast_w<<<(FF * D) / 2048, 256, 0, stream>>>(wu, W_U);
  cast_w<<<(FF * D) / 2048, 256, 0, stream>>>(wd, W_D);
  rmsnorm_cast<<<S, 256, 0, stream>>>(x, w_in, HB);
  gemm8<0><<<dim3(64, 1, 3), 512, 0, stream>>>(HB, W_QKV, QKVB, nullptr, S, D, D, D, D, 0,
                                               (long long)D * D, (long long)S * D);
  rope_apply<<<(S * 32 * 32) / 256, 256, 0, stream>>>(QKVB, QKVB + (size_t)S * D, RT);
  transpose_v<<<dim3(S / 64, 32), 256, 0, stream>>>(QKVB + 2 * (size_t)S * D, VT);
  flash_attn<<<dim3(S / 128, 32), 256, 0, stream>>>(QKVB, QKVB + (size_t)S * D, VT, ATTNB);
  if (splitO) {
    gemm8<3><<<dim3(64, 1, 4), 512, 0, stream>>>(ATTNB, W_O, OP, nullptr, S, D, 512, D, D, 512, 0, 0);
    reduce4<<<(S * D) / 1024, 256, 0, stream>>>(OP, x, X1, (size_t)S * D);
  } else {
    gemm8<1><<<dim3(64, 1, 1), 512, 0, stream>>>(ATTNB, W_O, X1, x, S, D, D, D, D, 0, 0, 0);
  }
  rmsnorm_cast<<<S, 256, 0, stream>>>(X1, w_pn, H2B);
  gemm8<0><<<dim3(256, 1, 1), 512, 0, stream>>>(H2B, W_G, GATEB, nullptr, S, FF, D, D, D, 0, 0, 0);
  gemm8<2><<<dim3(256, 1, 1), 512, 0, stream>>>(H2B, W_U, PRODB, GATEB, S, FF, D, D, D, 0, 0, 0);
  gemm8<3><<<dim3(64, 1, 4), 512, 0, stream>>>(PRODB, W_D, DP, nullptr, S, D, 2048, FF, FF, 2048, 0, 0);
  reduce4<<<(S * D) / 1024, 256, 0, stream>>>(DP, X1, out, (size_t)S * D);
  (void)in_sizes; (void)n_in; (void)out_size;
}

// Round 10
// 479.736 us; speedup vs baseline: 1.5035x; 1.0337x over previous
//
#include <hip/hip_runtime.h>

typedef unsigned short u16;
typedef unsigned int u32;
typedef __attribute__((ext_vector_type(2))) unsigned int u32x2;
typedef __attribute__((ext_vector_type(8))) unsigned short u16x8;
typedef __attribute__((ext_vector_type(8))) __bf16 bf16x8;
typedef __attribute__((ext_vector_type(4))) float f32x4;

#define DEV __device__ __forceinline__

DEV u16 f2bf(float f) {
  unsigned u = __builtin_bit_cast(unsigned, f);
  u += 0x7FFFu + ((u >> 16) & 1u);
  return (u16)(u >> 16);
}
DEV float bf2f(u16 h) {
  unsigned u = ((unsigned)h) << 16;
  return __builtin_bit_cast(float, u);
}
DEV u32 cvtpk(float lo, float hi) {
  u32 r;
  asm("v_cvt_pk_bf16_f32 %0, %1, %2" : "=v"(r) : "v"(lo), "v"(hi));
  return r;
}
DEV float exp2r(float x) {  // raw v_exp_f32: args bounded, no libm fixup needed
  float r;
  asm("v_exp_f32 %0, %1" : "=v"(r) : "v"(x));
  return r;
}
DEV float max3f(float a, float b, float c) {
  float r;
  asm("v_max3_f32 %0, %1, %2, %3" : "=v"(r) : "v"(a), "v"(b), "v"(c));
  return r;
}
DEV f32x4 mfma16(u16x8 a, u16x8 b, f32x4 c) {
  return __builtin_amdgcn_mfma_f32_16x16x32_bf16(
      __builtin_bit_cast(bf16x8, a), __builtin_bit_cast(bf16x8, b), c, 0, 0, 0);
}
DEV void gload_lds16(const void* g, void* l) {
  __builtin_amdgcn_global_load_lds(
      (const __attribute__((address_space(1))) void*)g,
      (__attribute__((address_space(3))) void*)l, 16, 0, 0);
}

// ---------------- weight cast fp32 -> bf16 ----------------
__global__ __launch_bounds__(256) void cast_w(const float* __restrict__ in, u16* __restrict__ out) {
  size_t i = ((size_t)blockIdx.x * 256 + threadIdx.x) * 8;
  float4 a = *(const float4*)(in + i);
  float4 b = *(const float4*)(in + i + 4);
  u16x8 o;
  o[0] = f2bf(a.x); o[1] = f2bf(a.y); o[2] = f2bf(a.z); o[3] = f2bf(a.w);
  o[4] = f2bf(b.x); o[5] = f2bf(b.y); o[6] = f2bf(b.z); o[7] = f2bf(b.w);
  *(u16x8*)(out + i) = o;
}

// ---------------- RMSNorm (fp32 in) -> bf16 out ----------------
__global__ __launch_bounds__(256) void rmsnorm_cast(const float* __restrict__ x, const float* __restrict__ w,
                                                    u16* __restrict__ out) {
  const int row = blockIdx.x, tid = threadIdx.x;
  const float* xr = x + (size_t)row * 2048;
  float4 a = *(const float4*)(xr + tid * 8);
  float4 b = *(const float4*)(xr + tid * 8 + 4);
  float ss = a.x * a.x + a.y * a.y + a.z * a.z + a.w * a.w +
             b.x * b.x + b.y * b.y + b.z * b.z + b.w * b.w;
#pragma unroll
  for (int off = 32; off; off >>= 1) ss += __shfl_xor(ss, off);
  __shared__ float part[4];
  if ((tid & 63) == 0) part[tid >> 6] = ss;
  __syncthreads();
  float tot = part[0] + part[1] + part[2] + part[3];
  float r = rsqrtf(tot * (1.0f / 2048.0f) + 1e-5f);
  float4 wa = *(const float4*)(w + tid * 8);
  float4 wb = *(const float4*)(w + tid * 8 + 4);
  u16x8 o;
  o[0] = f2bf(a.x * r * wa.x); o[1] = f2bf(a.y * r * wa.y);
  o[2] = f2bf(a.z * r * wa.z); o[3] = f2bf(a.w * r * wa.w);
  o[4] = f2bf(b.x * r * wb.x); o[5] = f2bf(b.y * r * wb.y);
  o[6] = f2bf(b.z * r * wb.z); o[7] = f2bf(b.w * r * wb.w);
  *(u16x8*)(out + (size_t)row * 2048 + tid * 8) = o;
}

// ============ 256x256-tile, 8-wave, 8-phase NT GEMM, BK=64 (m201 geometry) ============
template <int EPI>
__global__ __launch_bounds__(512) void gemm8(const u16* __restrict__ Ag, const u16* __restrict__ Bg,
                                             void* __restrict__ outp, const void* __restrict__ extra,
                                             int M, int N, int KC, int lda, int ldb, int koffStride,
                                             long long bStrideB, long long bStrideO) {
  __shared__ u16 lds[65536];  // 128 KiB: A0 @0, B0 @16384, A1 @32768, B1 @49152 (u16)
  const int z = blockIdx.z;
  const u16* Ap = Ag;
  const u16* Bp = Bg + (EPI == 0 ? (size_t)z * bStrideB : (size_t)0);
  const int koff = (EPI == 3) ? z * koffStride : 0;
  const int nbx = N >> 8;
  const int cpx = nbx >> 3;  // N-tiles per XCD band (nbx is 8 or 32)
  const int gid = blockIdx.x;
  const int bx = (gid & 7) * cpx + ((gid >> 3) % cpx);
  const int by = (gid >> 3) / cpx;
  const int bm = by << 8, bn = bx << 8;
  const int tid = threadIdx.x;
  const int w = tid >> 6, l = tid & 63;
  const int wr = w >> 2, wc = w & 3;
  const int l16 = l & 15, l4 = l >> 4;
  const int NTT = KC >> 6, NT2 = KC >> 7;  // tiles of 64; iterations (2 tiles each)
  const int srow = l >> 3;                              // row offset within 8-row group
  const int scolB = (((l & 7) ^ srow) << 4);            // pre-swizzled source byte offset

  auto STG = [&](int halfU16, const u16* src, int ldx, int rowBase, int kt) {
#pragma unroll
    for (int i = 0; i < 2; ++i) {
      const int r = i * 64 + w * 8 + srow;
      const char* g = (const char*)(src + (size_t)(rowBase + r) * ldx + kt) + scolB;
      gload_lds16(g, (char*)lds + halfU16 * 2 + (i * 512 + w * 64) * 16);
    }
  };

  f32x4 acc[8][4] = {};
  u16x8 a[4][2], b[4][2];

  auto LDA8 = [&](int bufU16, int mh) {
#pragma unroll
    for (int j = 0; j < 4; ++j) {
      const int row = wr * 128 + mh * 64 + j * 16 + l16;
#pragma unroll
      for (int kk = 0; kk < 2; ++kk)
        a[j][kk] = *(const u16x8*)&lds[bufU16 + row * 64 + (((kk * 4 + l4) ^ (row & 7)) << 3)];
    }
  };
  auto LDB4 = [&](int bufU16, int nh) {
#pragma unroll
    for (int j = 0; j < 2; ++j) {
      const int nf = nh * 2 + j;
      const int row = wc * 64 + nf * 16 + l16;
#pragma unroll
      for (int kk = 0; kk < 2; ++kk)
        b[nf][kk] = *(const u16x8*)&lds[bufU16 + row * 64 + (((kk * 4 + l4) ^ (row & 7)) << 3)];
    }
  };
  auto MM = [&](int mh, int nh) {
    __builtin_amdgcn_s_setprio(1);
#pragma unroll
    for (int kk = 0; kk < 2; ++kk)
#pragma unroll
      for (int mt = 0; mt < 4; ++mt)
#pragma unroll
        for (int j = 0; j < 2; ++j)
          acc[mh * 4 + mt][nh * 2 + j] = mfma16(a[mt][kk], b[nh * 2 + j][kk], acc[mh * 4 + mt][nh * 2 + j]);
    __builtin_amdgcn_s_setprio(0);
  };

  // Prologue: tile0 A+B -> buf0 (8 loads), tile1 A -> buf1 (4 loads)
  STG(0, Ap, lda, bm, koff);
  STG(8192, Ap, lda, bm + 128, koff);
  STG(16384, Bp, ldb, bn, koff);
  STG(24576, Bp, ldb, bn + 128, koff);
  STG(32768, Ap, lda, bm, koff + 64);
  STG(40960, Ap, lda, bm + 128, koff + 64);
  asm volatile("s_waitcnt vmcnt(4)" ::: "memory");
  __builtin_amdgcn_sched_barrier(0);
  __builtin_amdgcn_s_barrier();

  for (int it = 0; it < NT2; ++it) {
    const int t1 = 2 * it + 1, t2 = 2 * it + 2, t3 = 2 * it + 3;
    const int k1 = koff + t1 * 64;                       // always < KC
    const int k2 = koff + (t2 < NTT ? t2 * 64 : 0);
    const int k3 = koff + (t3 < NTT ? t3 * 64 : 0);
    // ph1
    LDA8(0, 0); LDB4(16384, 0);
    STG(49152, Bp, ldb, bn, k1);
    __builtin_amdgcn_s_barrier();
    MM(0, 0);
    __builtin_amdgcn_s_barrier();
    // ph2
    LDB4(16384, 1);
    STG(57344, Bp, ldb, bn + 128, k1);
    __builtin_amdgcn_s_barrier();
    MM(0, 1);
    __builtin_amdgcn_s_barrier();
    // ph3
    LDA8(0, 1);
    __builtin_amdgcn_s_barrier();
    MM(1, 0);
    __builtin_amdgcn_s_barrier();
    // ph4
    STG(0, Ap, lda, bm, k2);
    STG(8192, Ap, lda, bm + 128, k2);
    asm volatile("s_waitcnt vmcnt(4)" ::: "memory");
    __builtin_amdgcn_sched_barrier(0);
    __builtin_amdgcn_s_barrier();
    MM(1, 1);
    __builtin_amdgcn_s_barrier();
    // ph5
    LDA8(32768, 0); LDB4(49152, 0);
    STG(16384, Bp, ldb, bn, k2);
    __builtin_amdgcn_s_barrier();
    MM(0, 0);
    __builtin_amdgcn_s_barrier();
    // ph6
    LDB4(49152, 1);
    STG(24576, Bp, ldb, bn + 128, k2);
    __builtin_amdgcn_s_barrier();
    MM(0, 1);
    __builtin_amdgcn_s_barrier();
    // ph7
    LDA8(32768, 1);
    __builtin_amdgcn_s_barrier();
    MM(1, 0);
    __builtin_amdgcn_s_barrier();
    // ph8
    STG(32768, Ap, lda, bm, k3);
    STG(40960, Ap, lda, bm + 128, k3);
    asm volatile("s_waitcnt vmcnt(4)" ::: "memory");
    __builtin_amdgcn_sched_barrier(0);
    __builtin_amdgcn_s_barrier();
    MM(1, 1);
    __builtin_amdgcn_s_barrier();
  }

#pragma unroll
  for (int i = 0; i < 8; ++i)
#pragma unroll
    for (int j = 0; j < 4; ++j)
#pragma unroll
      for (int r = 0; r < 4; ++r) {
        const int row = bm + wr * 128 + i * 16 + l4 * 4 + r;
        const int col = bn + wc * 64 + j * 16 + l16;
        const size_t idx = (size_t)row * N + col;
        float v = acc[i][j][r];
        if (EPI == 0) {
          ((u16*)outp)[(size_t)z * bStrideO + idx] = f2bf(v);
        } else if (EPI == 1) {
          ((float*)outp)[idx] = v + ((const float*)extra)[idx];
        } else if (EPI == 2) {
          float g = bf2f(((const u16*)extra)[idx]);
          float sig = 1.0f / (1.0f + __expf(-v));
          ((u16*)outp)[idx] = f2bf(g * v * sig);
        } else {
          ((float*)outp)[(size_t)z * M * N + idx] = v;
        }
      }
}

// ---------------- split-K reduce: out = p0+p1+p2+p3 + res ----------------
__global__ __launch_bounds__(256) void reduce4(const float* __restrict__ p, const float* __restrict__ res,
                                               float* __restrict__ out, size_t n) {
  size_t i = ((size_t)blockIdx.x * 256 + threadIdx.x) * 4;
  float4 a = *(const float4*)(p + i);
  float4 b = *(const float4*)(p + n + i);
  float4 c = *(const float4*)(p + 2 * n + i);
  float4 d = *(const float4*)(p + 3 * n + i);
  float4 r = *(const float4*)(res + i);
  float4 o;
  o.x = a.x + b.x + c.x + d.x + r.x;
  o.y = a.y + b.y + c.y + d.y + r.y;
  o.z = a.z + b.z + c.z + d.z + r.z;
  o.w = a.w + b.w + c.w + d.w + r.w;
  *(float4*)(out + i) = o;
}

// ---------------- RoPE ----------------
__global__ __launch_bounds__(256) void rope_table(float2* __restrict__ tab) {
  int idx = blockIdx.x * 256 + threadIdx.x;  // S*32 = 65536
  int pos = idx >> 5, i = idx & 31;
  float inv = __expf(-(float)(2 * i) * (9.210340371976184f / 64.0f));
  float a = (float)pos * inv;
  float s, c;
  __sincosf(a, &s, &c);
  tab[idx] = make_float2(c, s);
}

__global__ __launch_bounds__(256) void rope_apply(u16* __restrict__ q, u16* __restrict__ k,
                                                  const float2* __restrict__ tab) {
  int idx = blockIdx.x * 256 + threadIdx.x;  // S*H*32 = 2M
  int i = idx & 31;
  int hh = (idx >> 5) & 31;
  int pos = idx >> 10;
  float2 cs = tab[(pos << 5) + i];
  size_t base = (size_t)pos * 2048 + hh * 64 + i;
  float a0 = bf2f(q[base]), a1 = bf2f(q[base + 32]);
  q[base] = f2bf(a0 * cs.x - a1 * cs.y);
  q[base + 32] = f2bf(a1 * cs.x + a0 * cs.y);
  float b0 = bf2f(k[base]), b1 = bf2f(k[base + 32]);
  k[base] = f2bf(b0 * cs.x - b1 * cs.y);
  k[base + 32] = f2bf(b1 * cs.x + b0 * cs.y);
}

// ---------------- V transpose: v[S][D] -> vT[h][d][S] ----------------
__global__ __launch_bounds__(256) void transpose_v(const u16* __restrict__ v, u16* __restrict__ vt) {
  __shared__ u16 t[64][72];
  const int t0 = blockIdx.x * 64, h = blockIdx.y, tid = threadIdx.x;
  {
    const int r = tid >> 3, c8 = (tid & 7) * 8;
#pragma unroll
    for (int j = 0; j < 2; ++j) {
      u16x8 val = *(const u16x8*)(v + (size_t)(t0 + r + 32 * j) * 2048 + h * 64 + c8);
      *(u16x8*)&t[r + 32 * j][c8] = val;
    }
  }
  __syncthreads();
  const int d = tid >> 2, q = (tid & 3) * 16;
  u16x8 lo, hi;
#pragma unroll
  for (int e = 0; e < 8; ++e) lo[e] = t[q + e][d];
#pragma unroll
  for (int e = 0; e < 8; ++e) hi[e] = t[q + 8 + e][d];
  *(u16x8*)(vt + (size_t)(h * 64 + d) * 2048 + t0 + q) = lo;
  *(u16x8*)(vt + (size_t)(h * 64 + d) * 2048 + t0 + q + 8) = hi;
}

// ---------------- Flash attention v7 ----------------
// v6 + (1) KV-loop unrolled x2 with static buf -> all LDS addresses loop-invariant,
// (2) raw v_exp_f32 (exp2r) for the hot exp path, (3) v_max3 trees for pmax.
__global__ __launch_bounds__(256) void flash_attn(const u16* __restrict__ qb, const u16* __restrict__ kb,
                                                  const u16* __restrict__ vt, u16* __restrict__ ob) {
  const int id = blockIdx.x + (blockIdx.y << 4);
  const int h = ((id & 7) << 2) | ((id >> 3) & 3);  // 4 heads per XCD -> K/V L2-resident
  const int q0 = (id >> 5) << 7;
  const int w = threadIdx.x >> 6, l = threadIdx.x & 63;
  const int l16 = l & 15, l4 = l >> 4;
  const float C = 0.125f * 1.4426950408889634f;  // folded into Q
  const float THR = 11.541560327111708f;         // 8 nats in exp2 domain
  __shared__ u16 KV[2][2][64 * 64];  // [buf][K|V][row][64], XOR-swizzled chunks
  __shared__ u32 P32[4][32 * 36];    // per-wave packed P, rows stride 36 u32
  const int srow8 = l >> 3;
  const int schunk = (l & 7) ^ srow8;

  auto STAGE = [&](int t0, int buf) {
#pragma unroll
    for (int j = 0; j < 2; ++j) {
      const int rg = w * 16 + j * 8;
      const int row = rg + srow8;
      gload_lds16(kb + (size_t)(t0 + row) * 2048 + h * 64 + schunk * 8, &KV[buf][0][rg * 64]);
      gload_lds16(vt + (size_t)(h * 64 + row) * 2048 + t0 + schunk * 8, &KV[buf][1][rg * 64]);
    }
  };

  u16x8 qf[2][2];
#pragma unroll
  for (int rt = 0; rt < 2; ++rt)
#pragma unroll
    for (int kh = 0; kh < 2; ++kh) {
      u16x8 q = *(const u16x8*)(qb + (size_t)(q0 + w * 32 + rt * 16 + l16) * 2048 + h * 64 + kh * 32 + l4 * 8);
#pragma unroll
      for (int e = 0; e < 8; ++e) q[e] = f2bf(bf2f(q[e]) * C);
      qf[rt][kh] = q;
    }
  float mrun[2], lrun[2];
  f32x4 oacc[2][4] = {};
#pragma unroll
  for (int i = 0; i < 2; ++i) { mrun[i] = -1e30f; lrun[i] = 0.f; }

  auto TILE = [&](int t0, int buf) {
    f32x4 sacc[2][4] = {};
#pragma unroll
    for (int kh = 0; kh < 2; ++kh)
#pragma unroll
      for (int tt = 0; tt < 4; ++tt) {
        const int row = tt * 16 + l16;
        const int ch = (kh * 4 + l4) ^ (row & 7);
        u16x8 kf = *(const u16x8*)&KV[buf][0][row * 64 + ch * 8];
#pragma unroll
        for (int rt = 0; rt < 2; ++rt)
          sacc[rt][tt] = mfma16(kf, qf[rt][kh], sacc[rt][tt]);  // swapped operands
      }
    float pmax[2];
    int ok = 1;
#pragma unroll
    for (int rt = 0; rt < 2; ++rt) {
      // v_max3 tree over 16 values: 5x max3 -> 2x max3 over (m0..m4, v15)
      float m0 = max3f(sacc[rt][0][0], sacc[rt][0][1], sacc[rt][0][2]);
      float m1 = max3f(sacc[rt][0][3], sacc[rt][1][0], sacc[rt][1][1]);
      float m2 = max3f(sacc[rt][1][2], sacc[rt][1][3], sacc[rt][2][0]);
      float m3 = max3f(sacc[rt][2][1], sacc[rt][2][2], sacc[rt][2][3]);
      float m4 = max3f(sacc[rt][3][0], sacc[rt][3][1], sacc[rt][3][2]);
      pmax[rt] = fmaxf(max3f(m0, m1, m2), max3f(m3, m4, sacc[rt][3][3]));
      ok &= (pmax[rt] <= mrun[rt] + THR) ? 1 : 0;
    }
    if (!__all(ok)) {
      float sfac[2];
#pragma unroll
      for (int rt = 0; rt < 2; ++rt) {
        float mx = pmax[rt];
        mx = fmaxf(mx, __shfl_xor(mx, 16));
        mx = fmaxf(mx, __shfl_xor(mx, 32));
        float mnew = fmaxf(mrun[rt], mx);
        sfac[rt] = exp2f(mrun[rt] - mnew);
        mrun[rt] = mnew;
        lrun[rt] *= sfac[rt];
      }
#pragma unroll
      for (int rt = 0; rt < 2; ++rt) {
        float sfo[4];
#pragma unroll
        for (int r = 0; r < 4; ++r) sfo[r] = __shfl(sfac[rt], (l & 48) + l4 * 4 + r);
#pragma unroll
        for (int nt = 0; nt < 4; ++nt)
#pragma unroll
          for (int r = 0; r < 4; ++r) oacc[rt][nt][r] *= sfo[r];
      }
    }
#pragma unroll
    for (int rt = 0; rt < 2; ++rt) {
      const int rowOff = (rt * 16 + l16) * 36 + l4 * 2;
#pragma unroll
      for (int tt = 0; tt < 4; ++tt) {
        float p0 = exp2r(sacc[rt][tt][0] - mrun[rt]);
        float p1 = exp2r(sacc[rt][tt][1] - mrun[rt]);
        float p2 = exp2r(sacc[rt][tt][2] - mrun[rt]);
        float p3 = exp2r(sacc[rt][tt][3] - mrun[rt]);
        lrun[rt] += (p0 + p1) + (p2 + p3);
        u32x2 pk;
        pk.x = cvtpk(p0, p1);
        pk.y = cvtpk(p2, p3);
        *(u32x2*)&P32[w][rowOff + tt * 8] = pk;
      }
    }
#pragma unroll
    for (int ks = 0; ks < 2; ++ks) {
      u16x8 pf[2];
#pragma unroll
      for (int rt = 0; rt < 2; ++rt)
        pf[rt] = *(const u16x8*)&P32[w][(rt * 16 + l16) * 36 + ks * 16 + l4 * 4];
#pragma unroll
      for (int nt = 0; nt < 4; ++nt) {
        const int row = nt * 16 + l16;
        const int ch = (ks * 4 + l4) ^ (row & 7);
        u16x8 vf = *(const u16x8*)&KV[buf][1][row * 64 + ch * 8];
#pragma unroll
        for (int rt = 0; rt < 2; ++rt)
          oacc[rt][nt] = mfma16(pf[rt], vf, oacc[rt][nt]);
      }
    }
  };

  STAGE(0, 0);
  __syncthreads();
  // x2-unrolled: buf is a compile-time constant in each body -> LDS addrs hoisted
  for (int t = 0; t < 32; t += 2) {
    STAGE((t + 1) * 64, 1);         // t+1 <= 31 always
    TILE(t * 64, 0);
    __syncthreads();
    if (t < 30) STAGE((t + 2) * 64, 0);
    TILE((t + 1) * 64, 1);
    __syncthreads();
  }
#pragma unroll
  for (int rt = 0; rt < 2; ++rt) {
    lrun[rt] += __shfl_xor(lrun[rt], 16);
    lrun[rt] += __shfl_xor(lrun[rt], 32);
  }
#pragma unroll
  for (int rt = 0; rt < 2; ++rt) {
    float linv[4];
#pragma unroll
    for (int r = 0; r < 4; ++r) linv[r] = 1.0f / __shfl(lrun[rt], (l & 48) + l4 * 4 + r);
#pragma unroll
    for (int r = 0; r < 4; ++r)
#pragma unroll
      for (int nt = 0; nt < 4; ++nt)
        ob[(size_t)(q0 + w * 32 + rt * 16 + l4 * 4 + r) * 2048 + h * 64 + nt * 16 + l16] =
            f2bf(oacc[rt][nt][r] * linv[r]);
  }
}

extern "C" void kernel_launch(void* const* d_in, const int* in_sizes, int n_in,
                              void* d_out, int out_size, void* d_ws, size_t ws_size,
                              hipStream_t stream) {
  const float* x    = (const float*)d_in[0];
  const float* w_in = (const float*)d_in[1];
  const float* wq   = (const float*)d_in[2];
  const float* wk   = (const float*)d_in[3];
  const float* wv   = (const float*)d_in[4];
  const float* wo   = (const float*)d_in[5];
  const float* w_pn = (const float*)d_in[6];
  const float* wg   = (const float*)d_in[7];
  const float* wu   = (const float*)d_in[8];
  const float* wd   = (const float*)d_in[9];
  float* out = (float*)d_out;
  char* ws = (char*)d_ws;
  const size_t MB = 1ull << 20;
  const int S = 2048, D = 2048, FF = 8192;

  u16* W_QKV = (u16*)(ws);               // 24 MB
  u16* W_O   = (u16*)(ws + 24 * MB);     // 8 MB
  u16* W_G   = (u16*)(ws + 32 * MB);     // 32 MB
  u16* W_U   = (u16*)(ws + 64 * MB);     // 32 MB
  u16* W_D   = (u16*)(ws + 96 * MB);     // 32 MB
  u16* HB    = (u16*)(ws + 128 * MB);    // 8 MB
  u16* QKVB  = (u16*)(ws + 136 * MB);    // 24 MB (q,k,v)
  u16* VT    = (u16*)(ws + 160 * MB);    // 8 MB
  u16* ATTNB = (u16*)(ws + 168 * MB);    // 8 MB
  float* X1  = (float*)(ws + 176 * MB);  // 16 MB
  u16* H2B   = (u16*)(ws + 192 * MB);    // 8 MB
  float2* RT = (float2*)(ws + 200 * MB); // 0.5 MB
  u16* GATEB = (u16*)(ws);               // 32 MB, overlays W_QKV+W_O (dead after O-proj)
  u16* PRODB = (u16*)(ws + 136 * MB);    // 32 MB, overlays QKVB+VT (dead after attention)
  float* DP  = (float*)(ws);             // 64 MB down-proj partials
  float* OP  = (float*)(ws + 208 * MB);  // 64 MB O-proj partials (only if ws permits)
  const bool splitO = ws_size >= 272 * MB;

  rope_table<<<65536 / 256, 256, 0, stream>>>(RT);
  cast_w<<<(D * D) / 2048, 256, 0, stream>>>(wq, W_QKV);
  cast_w<<<(D * D) / 2048, 256, 0, stream>>>(wk, W_QKV + (size_t)D * D);
  cast_w<<<(D * D) / 2048, 256, 0, stream>>>(wv, W_QKV + 2 * (size_t)D * D);
  cast_w<<<(D * D) / 2048, 256, 0, stream>>>(wo, W_O);
  cast_w<<<(FF * D) / 2048, 256, 0, stream>>>(wg, W_G);
  cast_w<<<(FF * D) / 2048, 256, 0, stream>>>(wu, W_U);
  cast_w<<<(FF * D) / 2048, 256, 0, stream>>>(wd, W_D);
  rmsnorm_cast<<<S, 256, 0, stream>>>(x, w_in, HB);
  gemm8<0><<<dim3(64, 1, 3), 512, 0, stream>>>(HB, W_QKV, QKVB, nullptr, S, D, D, D, D, 0,
                                               (long long)D * D, (long long)S * D);
  rope_apply<<<(S * 32 * 32) / 256, 256, 0, stream>>>(QKVB, QKVB + (size_t)S * D, RT);
  transpose_v<<<dim3(S / 64, 32), 256, 0, stream>>>(QKVB + 2 * (size_t)S * D, VT);
  flash_attn<<<dim3(S / 128, 32), 256, 0, stream>>>(QKVB, QKVB + (size_t)S * D, VT, ATTNB);
  if (splitO) {
    gemm8<3><<<dim3(64, 1, 4), 512, 0, stream>>>(ATTNB, W_O, OP, nullptr, S, D, 512, D, D, 512, 0, 0);
    reduce4<<<(S * D) / 1024, 256, 0, stream>>>(OP, x, X1, (size_t)S * D);
  } else {
    gemm8<1><<<dim3(64, 1, 1), 512, 0, stream>>>(ATTNB, W_O, X1, x, S, D, D, D, D, 0, 0, 0);
  }
  rmsnorm_cast<<<S, 256, 0, stream>>>(X1, w_pn, H2B);
  gemm8<0><<<dim3(256, 1, 1), 512, 0, stream>>>(H2B, W_G, GATEB, nullptr, S, FF, D, D, D, 0, 0, 0);
  gemm8<2><<<dim3(256, 1, 1), 512, 0, stream>>>(H2B, W_U, PRODB, GATEB, S, FF, D, D, D, 0, 0, 0);
  gemm8<3><<<dim3(64, 1, 4), 512, 0, stream>>>(PRODB, W_D, DP, nullptr, S, D, 2048, FF, FF, 2048, 0, 0);
  reduce4<<<(S * D) / 1024, 256, 0, stream>>>(DP, X1, out, (size_t)S * D);
  (void)in_sizes; (void)n_in; (void)out_size;
}

// Round 12
// 465.625 us; speedup vs baseline: 1.5491x; 1.0303x over previous
//
#include <hip/hip_runtime.h>

typedef unsigned short u16;
typedef unsigned int u32;
typedef __attribute__((ext_vector_type(2))) unsigned int u32x2;
typedef __attribute__((ext_vector_type(8))) unsigned short u16x8;
typedef __attribute__((ext_vector_type(8))) __bf16 bf16x8;
typedef __attribute__((ext_vector_type(4))) float f32x4;

#define DEV __device__ __forceinline__

DEV u16 f2bf(float f) {
  unsigned u = __builtin_bit_cast(unsigned, f);
  u += 0x7FFFu + ((u >> 16) & 1u);
  return (u16)(u >> 16);
}
DEV float bf2f(u16 h) {
  unsigned u = ((unsigned)h) << 16;
  return __builtin_bit_cast(float, u);
}
DEV u32 cvtpk(float lo, float hi) {
  u32 r;
  asm("v_cvt_pk_bf16_f32 %0, %1, %2" : "=v"(r) : "v"(lo), "v"(hi));
  return r;
}
DEV float exp2r(float x) {  // raw v_exp_f32: args bounded, no libm fixup needed
  float r;
  asm("v_exp_f32 %0, %1" : "=v"(r) : "v"(x));
  return r;
}
DEV float max3f(float a, float b, float c) {
  float r;
  asm("v_max3_f32 %0, %1, %2, %3" : "=v"(r) : "v"(a), "v"(b), "v"(c));
  return r;
}
DEV f32x4 mfma16(u16x8 a, u16x8 b, f32x4 c) {
  return __builtin_amdgcn_mfma_f32_16x16x32_bf16(
      __builtin_bit_cast(bf16x8, a), __builtin_bit_cast(bf16x8, b), c, 0, 0, 0);
}
DEV void gload_lds16(const void* g, void* l) {
  __builtin_amdgcn_global_load_lds(
      (const __attribute__((address_space(1))) void*)g,
      (__attribute__((address_space(3))) void*)l, 16, 0, 0);
}

// ---------------- fused weight cast fp32 -> bf16 (all 7 weights, one dispatch) ----------------
// segments (blocks of 2048 elems): wq,wk,wv,wo = 2048 blocks each; wg,wu,wd = 8192 each.
__global__ __launch_bounds__(256) void cast_all(const float* __restrict__ wq, const float* __restrict__ wk,
                                                const float* __restrict__ wv, const float* __restrict__ wo,
                                                const float* __restrict__ wg, const float* __restrict__ wu,
                                                const float* __restrict__ wd, u16* __restrict__ outQKV,
                                                u16* __restrict__ outO, u16* __restrict__ outG,
                                                u16* __restrict__ outU, u16* __restrict__ outD) {
  const int b = blockIdx.x;
  const float* src;
  u16* dst;
  int lb;
  if (b < 6144) {            // wq|wk|wv -> contiguous W_QKV
    src = (b < 2048) ? wq : (b < 4096) ? wk : wv;
    lb = b & 2047;
    dst = outQKV + (size_t)(b >> 11) * 4194304;
  } else if (b < 8192) {
    src = wo; lb = b - 6144; dst = outO;
  } else if (b < 16384) {
    src = wg; lb = b - 8192; dst = outG;
  } else if (b < 24576) {
    src = wu; lb = b - 16384; dst = outU;
  } else {
    src = wd; lb = b - 24576; dst = outD;
  }
  size_t i = ((size_t)lb * 256 + threadIdx.x) * 8;
  float4 a = *(const float4*)(src + i);
  float4 c = *(const float4*)(src + i + 4);
  u16x8 o;
  o[0] = f2bf(a.x); o[1] = f2bf(a.y); o[2] = f2bf(a.z); o[3] = f2bf(a.w);
  o[4] = f2bf(c.x); o[5] = f2bf(c.y); o[6] = f2bf(c.z); o[7] = f2bf(c.w);
  *(u16x8*)(dst + i) = o;
}

// ---------------- RMSNorm (fp32 in) -> bf16 out ----------------
__global__ __launch_bounds__(256) void rmsnorm_cast(const float* __restrict__ x, const float* __restrict__ w,
                                                    u16* __restrict__ out) {
  const int row = blockIdx.x, tid = threadIdx.x;
  const float* xr = x + (size_t)row * 2048;
  float4 a = *(const float4*)(xr + tid * 8);
  float4 b = *(const float4*)(xr + tid * 8 + 4);
  float ss = a.x * a.x + a.y * a.y + a.z * a.z + a.w * a.w +
             b.x * b.x + b.y * b.y + b.z * b.z + b.w * b.w;
#pragma unroll
  for (int off = 32; off; off >>= 1) ss += __shfl_xor(ss, off);
  __shared__ float part[4];
  if ((tid & 63) == 0) part[tid >> 6] = ss;
  __syncthreads();
  float tot = part[0] + part[1] + part[2] + part[3];
  float r = rsqrtf(tot * (1.0f / 2048.0f) + 1e-5f);
  float4 wa = *(const float4*)(w + tid * 8);
  float4 wb = *(const float4*)(w + tid * 8 + 4);
  u16x8 o;
  o[0] = f2bf(a.x * r * wa.x); o[1] = f2bf(a.y * r * wa.y);
  o[2] = f2bf(a.z * r * wa.z); o[3] = f2bf(a.w * r * wa.w);
  o[4] = f2bf(b.x * r * wb.x); o[5] = f2bf(b.y * r * wb.y);
  o[6] = f2bf(b.z * r * wb.z); o[7] = f2bf(b.w * r * wb.w);
  *(u16x8*)(out + (size_t)row * 2048 + tid * 8) = o;
}

// ============ 256x256-tile, 8-wave, 8-phase NT GEMM, BK=64 (round-10-verified schedule) ============
// vmcnt(4) at prologue/ph4/ph8 ONLY — the race-free configuration measured at 480us.
template <int EPI>
__global__ __launch_bounds__(512) void gemm8(const u16* __restrict__ Ag, const u16* __restrict__ Bg,
                                             void* __restrict__ outp, const void* __restrict__ extra,
                                             int M, int N, int KC, int lda, int ldb, int koffStride,
                                             long long bStrideB, long long bStrideO) {
  __shared__ u16 lds[65536];  // 128 KiB: A0 @0, B0 @16384, A1 @32768, B1 @49152 (u16)
  const int z = blockIdx.z;
  const u16* Ap = Ag;
  const u16* Bp = Bg + (EPI == 0 ? (size_t)z * bStrideB : (size_t)0);
  const int koff = (EPI == 3) ? z * koffStride : 0;
  const int nbx = N >> 8;
  const int cpx = nbx >> 3;  // N-tiles per XCD band (nbx is 8 or 32)
  const int gid = blockIdx.x;
  const int bx = (gid & 7) * cpx + ((gid >> 3) % cpx);
  const int by = (gid >> 3) / cpx;
  const int bm = by << 8, bn = bx << 8;
  const int tid = threadIdx.x;
  const int w = tid >> 6, l = tid & 63;
  const int wr = w >> 2, wc = w & 3;
  const int l16 = l & 15, l4 = l >> 4;
  const int NTT = KC >> 6, NT2 = KC >> 7;  // tiles of 64; iterations (2 tiles each)
  const int srow = l >> 3;                              // row offset within 8-row group
  const int scolB = (((l & 7) ^ srow) << 4);            // pre-swizzled source byte offset

  auto STG = [&](int halfU16, const u16* src, int ldx, int rowBase, int kt) {
#pragma unroll
    for (int i = 0; i < 2; ++i) {
      const int r = i * 64 + w * 8 + srow;
      const char* g = (const char*)(src + (size_t)(rowBase + r) * ldx + kt) + scolB;
      gload_lds16(g, (char*)lds + halfU16 * 2 + (i * 512 + w * 64) * 16);
    }
  };

  f32x4 acc[8][4] = {};
  u16x8 a[4][2], b[4][2];

  auto LDA8 = [&](int bufU16, int mh) {
#pragma unroll
    for (int j = 0; j < 4; ++j) {
      const int row = wr * 128 + mh * 64 + j * 16 + l16;
#pragma unroll
      for (int kk = 0; kk < 2; ++kk)
        a[j][kk] = *(const u16x8*)&lds[bufU16 + row * 64 + (((kk * 4 + l4) ^ (row & 7)) << 3)];
    }
  };
  auto LDB4 = [&](int bufU16, int nh) {
#pragma unroll
    for (int j = 0; j < 2; ++j) {
      const int nf = nh * 2 + j;
      const int row = wc * 64 + nf * 16 + l16;
#pragma unroll
      for (int kk = 0; kk < 2; ++kk)
        b[nf][kk] = *(const u16x8*)&lds[bufU16 + row * 64 + (((kk * 4 + l4) ^ (row & 7)) << 3)];
    }
  };
  auto MM = [&](int mh, int nh) {
    __builtin_amdgcn_s_setprio(1);
#pragma unroll
    for (int kk = 0; kk < 2; ++kk)
#pragma unroll
      for (int mt = 0; mt < 4; ++mt)
#pragma unroll
        for (int j = 0; j < 2; ++j)
          acc[mh * 4 + mt][nh * 2 + j] = mfma16(a[mt][kk], b[nh * 2 + j][kk], acc[mh * 4 + mt][nh * 2 + j]);
    __builtin_amdgcn_s_setprio(0);
  };

  // Prologue: tile0 A+B -> buf0 (8 loads), tile1 A -> buf1 (4 loads)
  STG(0, Ap, lda, bm, koff);
  STG(8192, Ap, lda, bm + 128, koff);
  STG(16384, Bp, ldb, bn, koff);
  STG(24576, Bp, ldb, bn + 128, koff);
  STG(32768, Ap, lda, bm, koff + 64);
  STG(40960, Ap, lda, bm + 128, koff + 64);
  asm volatile("s_waitcnt vmcnt(4)" ::: "memory");
  __builtin_amdgcn_sched_barrier(0);
  __builtin_amdgcn_s_barrier();

  for (int it = 0; it < NT2; ++it) {
    const int t1 = 2 * it + 1, t2 = 2 * it + 2, t3 = 2 * it + 3;
    const int k1 = koff + t1 * 64;                       // always < KC
    const int k2 = koff + (t2 < NTT ? t2 * 64 : 0);
    const int k3 = koff + (t3 < NTT ? t3 * 64 : 0);
    // ph1
    LDA8(0, 0); LDB4(16384, 0);
    STG(49152, Bp, ldb, bn, k1);
    __builtin_amdgcn_s_barrier();
    MM(0, 0);
    __builtin_amdgcn_s_barrier();
    // ph2
    LDB4(16384, 1);
    STG(57344, Bp, ldb, bn + 128, k1);
    __builtin_amdgcn_s_barrier();
    MM(0, 1);
    __builtin_amdgcn_s_barrier();
    // ph3
    LDA8(0, 1);
    __builtin_amdgcn_s_barrier();
    MM(1, 0);
    __builtin_amdgcn_s_barrier();
    // ph4
    STG(0, Ap, lda, bm, k2);
    STG(8192, Ap, lda, bm + 128, k2);
    asm volatile("s_waitcnt vmcnt(4)" ::: "memory");
    __builtin_amdgcn_sched_barrier(0);
    __builtin_amdgcn_s_barrier();
    MM(1, 1);
    __builtin_amdgcn_s_barrier();
    // ph5
    LDA8(32768, 0); LDB4(49152, 0);
    STG(16384, Bp, ldb, bn, k2);
    __builtin_amdgcn_s_barrier();
    MM(0, 0);
    __builtin_amdgcn_s_barrier();
    // ph6
    LDB4(49152, 1);
    STG(24576, Bp, ldb, bn + 128, k2);
    __builtin_amdgcn_s_barrier();
    MM(0, 1);
    __builtin_amdgcn_s_barrier();
    // ph7
    LDA8(32768, 1);
    __builtin_amdgcn_s_barrier();
    MM(1, 0);
    __builtin_amdgcn_s_barrier();
    // ph8
    STG(32768, Ap, lda, bm, k3);
    STG(40960, Ap, lda, bm + 128, k3);
    asm volatile("s_waitcnt vmcnt(4)" ::: "memory");
    __builtin_amdgcn_sched_barrier(0);
    __builtin_amdgcn_s_barrier();
    MM(1, 1);
    __builtin_amdgcn_s_barrier();
  }

#pragma unroll
  for (int i = 0; i < 8; ++i)
#pragma unroll
    for (int j = 0; j < 4; ++j)
#pragma unroll
      for (int r = 0; r < 4; ++r) {
        const int row = bm + wr * 128 + i * 16 + l4 * 4 + r;
        const int col = bn + wc * 64 + j * 16 + l16;
        const size_t idx = (size_t)row * N + col;
        float v = acc[i][j][r];
        if (EPI == 0) {
          ((u16*)outp)[(size_t)z * bStrideO + idx] = f2bf(v);
        } else if (EPI == 1) {
          ((float*)outp)[idx] = v + ((const float*)extra)[idx];
        } else if (EPI == 2) {
          float g = bf2f(((const u16*)extra)[idx]);
          float sig = 1.0f / (1.0f + __expf(-v));
          ((u16*)outp)[idx] = f2bf(g * v * sig);
        } else {
          ((float*)outp)[(size_t)z * M * N + idx] = v;
        }
      }
}

// ---------------- split-K reduce: out = p0+p1+p2+p3 + res ----------------
__global__ __launch_bounds__(256) void reduce4(const float* __restrict__ p, const float* __restrict__ res,
                                               float* __restrict__ out, size_t n) {
  size_t i = ((size_t)blockIdx.x * 256 + threadIdx.x) * 4;
  float4 a = *(const float4*)(p + i);
  float4 b = *(const float4*)(p + n + i);
  float4 c = *(const float4*)(p + 2 * n + i);
  float4 d = *(const float4*)(p + 3 * n + i);
  float4 r = *(const float4*)(res + i);
  float4 o;
  o.x = a.x + b.x + c.x + d.x + r.x;
  o.y = a.y + b.y + c.y + d.y + r.y;
  o.z = a.z + b.z + c.z + d.z + r.z;
  o.w = a.w + b.w + c.w + d.w + r.w;
  *(float4*)(out + i) = o;
}

// ---------------- RoPE ----------------
__global__ __launch_bounds__(256) void rope_table(float2* __restrict__ tab) {
  int idx = blockIdx.x * 256 + threadIdx.x;  // S*32 = 65536
  int pos = idx >> 5, i = idx & 31;
  float inv = __expf(-(float)(2 * i) * (9.210340371976184f / 64.0f));
  float a = (float)pos * inv;
  float s, c;
  __sincosf(a, &s, &c);
  tab[idx] = make_float2(c, s);
}

__global__ __launch_bounds__(256) void rope_apply(u16* __restrict__ q, u16* __restrict__ k,
                                                  const float2* __restrict__ tab) {
  int idx = blockIdx.x * 256 + threadIdx.x;  // S*H*32 = 2M
  int i = idx & 31;
  int hh = (idx >> 5) & 31;
  int pos = idx >> 10;
  float2 cs = tab[(pos << 5) + i];
  size_t base = (size_t)pos * 2048 + hh * 64 + i;
  float a0 = bf2f(q[base]), a1 = bf2f(q[base + 32]);
  q[base] = f2bf(a0 * cs.x - a1 * cs.y);
  q[base + 32] = f2bf(a1 * cs.x + a0 * cs.y);
  float b0 = bf2f(k[base]), b1 = bf2f(k[base + 32]);
  k[base] = f2bf(b0 * cs.x - b1 * cs.y);
  k[base + 32] = f2bf(b1 * cs.x + b0 * cs.y);
}

// ---------------- V transpose: v[S][D] -> vT[h][d][S] ----------------
__global__ __launch_bounds__(256) void transpose_v(const u16* __restrict__ v, u16* __restrict__ vt) {
  __shared__ u16 t[64][72];
  const int t0 = blockIdx.x * 64, h = blockIdx.y, tid = threadIdx.x;
  {
    const int r = tid >> 3, c8 = (tid & 7) * 8;
#pragma unroll
    for (int j = 0; j < 2; ++j) {
      u16x8 val = *(const u16x8*)(v + (size_t)(t0 + r + 32 * j) * 2048 + h * 64 + c8);
      *(u16x8*)&t[r + 32 * j][c8] = val;
    }
  }
  __syncthreads();
  const int d = tid >> 2, q = (tid & 3) * 16;
  u16x8 lo, hi;
#pragma unroll
  for (int e = 0; e < 8; ++e) lo[e] = t[q + e][d];
#pragma unroll
  for (int e = 0; e < 8; ++e) hi[e] = t[q + 8 + e][d];
  *(u16x8*)(vt + (size_t)(h * 64 + d) * 2048 + t0 + q) = lo;
  *(u16x8*)(vt + (size_t)(h * 64 + d) * 2048 + t0 + q + 8) = hi;
}

// ---------------- Flash attention v7 ----------------
__global__ __launch_bounds__(256) void flash_attn(const u16* __restrict__ qb, const u16* __restrict__ kb,
                                                  const u16* __restrict__ vt, u16* __restrict__ ob) {
  const int id = blockIdx.x + (blockIdx.y << 4);
  const int h = ((id & 7) << 2) | ((id >> 3) & 3);  // 4 heads per XCD -> K/V L2-resident
  const int q0 = (id >> 5) << 7;
  const int w = threadIdx.x >> 6, l = threadIdx.x & 63;
  const int l16 = l & 15, l4 = l >> 4;
  const float C = 0.125f * 1.4426950408889634f;  // folded into Q
  const float THR = 11.541560327111708f;         // 8 nats in exp2 domain
  __shared__ u16 KV[2][2][64 * 64];  // [buf][K|V][row][64], XOR-swizzled chunks
  __shared__ u32 P32[4][32 * 36];    // per-wave packed P, rows stride 36 u32
  const int srow8 = l >> 3;
  const int schunk = (l & 7) ^ srow8;

  auto STAGE = [&](int t0, int buf) {
#pragma unroll
    for (int j = 0; j < 2; ++j) {
      const int rg = w * 16 + j * 8;
      const int row = rg + srow8;
      gload_lds16(kb + (size_t)(t0 + row) * 2048 + h * 64 + schunk * 8, &KV[buf][0][rg * 64]);
      gload_lds16(vt + (size_t)(h * 64 + row) * 2048 + t0 + schunk * 8, &KV[buf][1][rg * 64]);
    }
  };

  u16x8 qf[2][2];
#pragma unroll
  for (int rt = 0; rt < 2; ++rt)
#pragma unroll
    for (int kh = 0; kh < 2; ++kh) {
      u16x8 q = *(const u16x8*)(qb + (size_t)(q0 + w * 32 + rt * 16 + l16) * 2048 + h * 64 + kh * 32 + l4 * 8);
#pragma unroll
      for (int e = 0; e < 8; ++e) q[e] = f2bf(bf2f(q[e]) * C);
      qf[rt][kh] = q;
    }
  float mrun[2], lrun[2];
  f32x4 oacc[2][4] = {};
#pragma unroll
  for (int i = 0; i < 2; ++i) { mrun[i] = -1e30f; lrun[i] = 0.f; }

  auto TILE = [&](int t0, int buf) {
    f32x4 sacc[2][4] = {};
#pragma unroll
    for (int kh = 0; kh < 2; ++kh)
#pragma unroll
      for (int tt = 0; tt < 4; ++tt) {
        const int row = tt * 16 + l16;
        const int ch = (kh * 4 + l4) ^ (row & 7);
        u16x8 kf = *(const u16x8*)&KV[buf][0][row * 64 + ch * 8];
#pragma unroll
        for (int rt = 0; rt < 2; ++rt)
          sacc[rt][tt] = mfma16(kf, qf[rt][kh], sacc[rt][tt]);  // swapped operands
      }
    float pmax[2];
    int ok = 1;
#pragma unroll
    for (int rt = 0; rt < 2; ++rt) {
      float m0 = max3f(sacc[rt][0][0], sacc[rt][0][1], sacc[rt][0][2]);
      float m1 = max3f(sacc[rt][0][3], sacc[rt][1][0], sacc[rt][1][1]);
      float m2 = max3f(sacc[rt][1][2], sacc[rt][1][3], sacc[rt][2][0]);
      float m3 = max3f(sacc[rt][2][1], sacc[rt][2][2], sacc[rt][2][3]);
      float m4 = max3f(sacc[rt][3][0], sacc[rt][3][1], sacc[rt][3][2]);
      pmax[rt] = fmaxf(max3f(m0, m1, m2), max3f(m3, m4, sacc[rt][3][3]));
      ok &= (pmax[rt] <= mrun[rt] + THR) ? 1 : 0;
    }
    if (!__all(ok)) {
      float sfac[2];
#pragma unroll
      for (int rt = 0; rt < 2; ++rt) {
        float mx = pmax[rt];
        mx = fmaxf(mx, __shfl_xor(mx, 16));
        mx = fmaxf(mx, __shfl_xor(mx, 32));
        float mnew = fmaxf(mrun[rt], mx);
        sfac[rt] = exp2f(mrun[rt] - mnew);
        mrun[rt] = mnew;
        lrun[rt] *= sfac[rt];
      }
#pragma unroll
      for (int rt = 0; rt < 2; ++rt) {
        float sfo[4];
#pragma unroll
        for (int r = 0; r < 4; ++r) sfo[r] = __shfl(sfac[rt], (l & 48) + l4 * 4 + r);
#pragma unroll
        for (int nt = 0; nt < 4; ++nt)
#pragma unroll
          for (int r = 0; r < 4; ++r) oacc[rt][nt][r] *= sfo[r];
      }
    }
#pragma unroll
    for (int rt = 0; rt < 2; ++rt) {
      const int rowOff = (rt * 16 + l16) * 36 + l4 * 2;
#pragma unroll
      for (int tt = 0; tt < 4; ++tt) {
        float p0 = exp2r(sacc[rt][tt][0] - mrun[rt]);
        float p1 = exp2r(sacc[rt][tt][1] - mrun[rt]);
        float p2 = exp2r(sacc[rt][tt][2] - mrun[rt]);
        float p3 = exp2r(sacc[rt][tt][3] - mrun[rt]);
        lrun[rt] += (p0 + p1) + (p2 + p3);
        u32x2 pk;
        pk.x = cvtpk(p0, p1);
        pk.y = cvtpk(p2, p3);
        *(u32x2*)&P32[w][rowOff + tt * 8] = pk;
      }
    }
#pragma unroll
    for (int ks = 0; ks < 2; ++ks) {
      u16x8 pf[2];
#pragma unroll
      for (int rt = 0; rt < 2; ++rt)
        pf[rt] = *(const u16x8*)&P32[w][(rt * 16 + l16) * 36 + ks * 16 + l4 * 4];
#pragma unroll
      for (int nt = 0; nt < 4; ++nt) {
        const int row = nt * 16 + l16;
        const int ch = (ks * 4 + l4) ^ (row & 7);
        u16x8 vf = *(const u16x8*)&KV[buf][1][row * 64 + ch * 8];
#pragma unroll
        for (int rt = 0; rt < 2; ++rt)
          oacc[rt][nt] = mfma16(pf[rt], vf, oacc[rt][nt]);
      }
    }
  };

  STAGE(0, 0);
  __syncthreads();
  for (int t = 0; t < 32; t += 2) {
    STAGE((t + 1) * 64, 1);
    TILE(t * 64, 0);
    __syncthreads();
    if (t < 30) STAGE((t + 2) * 64, 0);
    TILE((t + 1) * 64, 1);
    __syncthreads();
  }
#pragma unroll
  for (int rt = 0; rt < 2; ++rt) {
    lrun[rt] += __shfl_xor(lrun[rt], 16);
    lrun[rt] += __shfl_xor(lrun[rt], 32);
  }
#pragma unroll
  for (int rt = 0; rt < 2; ++rt) {
    float linv[4];
#pragma unroll
    for (int r = 0; r < 4; ++r) linv[r] = 1.0f / __shfl(lrun[rt], (l & 48) + l4 * 4 + r);
#pragma unroll
    for (int r = 0; r < 4; ++r)
#pragma unroll
      for (int nt = 0; nt < 4; ++nt)
        ob[(size_t)(q0 + w * 32 + rt * 16 + l4 * 4 + r) * 2048 + h * 64 + nt * 16 + l16] =
            f2bf(oacc[rt][nt][r] * linv[r]);
  }
}

extern "C" void kernel_launch(void* const* d_in, const int* in_sizes, int n_in,
                              void* d_out, int out_size, void* d_ws, size_t ws_size,
                              hipStream_t stream) {
  const float* x    = (const float*)d_in[0];
  const float* w_in = (const float*)d_in[1];
  const float* wq   = (const float*)d_in[2];
  const float* wk   = (const float*)d_in[3];
  const float* wv   = (const float*)d_in[4];
  const float* wo   = (const float*)d_in[5];
  const float* w_pn = (const float*)d_in[6];
  const float* wg   = (const float*)d_in[7];
  const float* wu   = (const float*)d_in[8];
  const float* wd   = (const float*)d_in[9];
  float* out = (float*)d_out;
  char* ws = (char*)d_ws;
  const size_t MB = 1ull << 20;
  const int S = 2048, D = 2048, FF = 8192;

  u16* W_QKV = (u16*)(ws);               // 24 MB
  u16* W_O   = (u16*)(ws + 24 * MB);     // 8 MB
  u16* W_G   = (u16*)(ws + 32 * MB);     // 32 MB
  u16* W_U   = (u16*)(ws + 64 * MB);     // 32 MB
  u16* W_D   = (u16*)(ws + 96 * MB);     // 32 MB
  u16* HB    = (u16*)(ws + 128 * MB);    // 8 MB
  u16* QKVB  = (u16*)(ws + 136 * MB);    // 24 MB (q,k,v)
  u16* VT    = (u16*)(ws + 160 * MB);    // 8 MB
  u16* ATTNB = (u16*)(ws + 168 * MB);    // 8 MB
  float* X1  = (float*)(ws + 176 * MB);  // 16 MB
  u16* H2B   = (u16*)(ws + 192 * MB);    // 8 MB
  float2* RT = (float2*)(ws + 200 * MB); // 0.5 MB
  u16* GATEB = (u16*)(ws);               // 32 MB, overlays W_QKV+W_O (dead after O-proj)
  u16* PRODB = (u16*)(ws + 136 * MB);    // 32 MB, overlays QKVB+VT (dead after attention)
  float* DP  = (float*)(ws);             // 64 MB down-proj partials
  float* OP  = (float*)(ws + 208 * MB);  // 64 MB O-proj partials (only if ws permits)
  const bool splitO = ws_size >= 272 * MB;

  rope_table<<<65536 / 256, 256, 0, stream>>>(RT);
  cast_all<<<32768, 256, 0, stream>>>(wq, wk, wv, wo, wg, wu, wd, W_QKV, W_O, W_G, W_U, W_D);
  rmsnorm_cast<<<S, 256, 0, stream>>>(x, w_in, HB);
  gemm8<0><<<dim3(64, 1, 3), 512, 0, stream>>>(HB, W_QKV, QKVB, nullptr, S, D, D, D, D, 0,
                                               (long long)D * D, (long long)S * D);
  rope_apply<<<(S * 32 * 32) / 256, 256, 0, stream>>>(QKVB, QKVB + (size_t)S * D, RT);
  transpose_v<<<dim3(S / 64, 32), 256, 0, stream>>>(QKVB + 2 * (size_t)S * D, VT);
  flash_attn<<<dim3(S / 128, 32), 256, 0, stream>>>(QKVB, QKVB + (size_t)S * D, VT, ATTNB);
  if (splitO) {
    gemm8<3><<<dim3(64, 1, 4), 512, 0, stream>>>(ATTNB, W_O, OP, nullptr, S, D, 512, D, D, 512, 0, 0);
    reduce4<<<(S * D) / 1024, 256, 0, stream>>>(OP, x, X1, (size_t)S * D);
  } else {
    gemm8<1><<<dim3(64, 1, 1), 512, 0, stream>>>(ATTNB, W_O, X1, x, S, D, D, D, D, 0, 0, 0);
  }
  rmsnorm_cast<<<S, 256, 0, stream>>>(X1, w_pn, H2B);
  gemm8<0><<<dim3(256, 1, 1), 512, 0, stream>>>(H2B, W_G, GATEB, nullptr, S, FF, D, D, D, 0, 0, 0);
  gemm8<2><<<dim3(256, 1, 1), 512, 0, stream>>>(H2B, W_U, PRODB, GATEB, S, FF, D, D, D, 0, 0, 0);
  gemm8<3><<<dim3(64, 1, 4), 512, 0, stream>>>(PRODB, W_D, DP, nullptr, S, D, 2048, FF, FF, 2048, 0, 0);
  reduce4<<<(S * D) / 1024, 256, 0, stream>>>(DP, X1, out, (size_t)S * D);
  (void)in_sizes; (void)n_in; (void)out_size;
}